// Round 14
// baseline (2084.132 us; speedup 1.0000x reference)
//
#include <hip/hip_runtime.h>
#include <stdint.h>

#define NN 100000
#define NNP 100096          // NN padded to multiple of 128
#define NE 200000
#define NEP 200064          // NE padded to multiple of 128
#define NT 600000
#define HID 256

typedef __attribute__((ext_vector_type(8))) short bf16x8;
typedef __attribute__((ext_vector_type(4))) float f32x4;

__device__ __forceinline__ float bf2f(unsigned short u) {
    union { unsigned int i; float f; } x; x.i = ((unsigned int)u) << 16; return x.f;
}
__device__ __forceinline__ unsigned short f2bf(float f) {
    union { float f; unsigned int i; } x; x.f = f;
    unsigned int r = (x.i + 0x7FFFu + ((x.i >> 16) & 1u)) >> 16;
    return (unsigned short)r;
}

// async global->LDS, 16B per lane; LDS dest = wave-uniform base + lane*16
__device__ __forceinline__ void gload16(const void* g, void* l) {
    __builtin_amdgcn_global_load_lds(
        (const __attribute__((address_space(1))) void*)g,
        (__attribute__((address_space(3))) void*)l, 16, 0, 0);
}

// ---------------------------------------------------------------------------
// Multi-tile m97-style GEMM core: each block processes T M-tiles (stride 8,
// all on its own XCD: g = g0 + t*8, xcd = g&7 const). Per tile: BK=64 K-loop,
// 2 barriers/kt. OVERLAP: after the last compute-barrier of tile t we issue
// tile t+1's first stage, THEN run tile t's epilogue while loads fly, then
// one drain barrier. Prologue paid once per block instead of per tile.
// ROUND-12 LESSON: keep direct operand order (C^T swap regressed).
// REGISTER BUDGET [rounds 8/10]: pool = 512 wave-regs/SIMD, unified VGPR+AGPR;
// 64 acc + ~60 VGPR = ~124; bounds(256,4) caps 128. (256,5)/(512,6) spilled.
// ---------------------------------------------------------------------------
template<int FLAGS, bool CBF>
__device__ __forceinline__
void gemm128_mt_core(const unsigned short* __restrict__ A,
                     const unsigned short* __restrict__ BT,
                     const float* __restrict__ bias,
                     const unsigned short* __restrict__ res,
                     void* __restrict__ Cv,
                     int g0, int T, int Mtiles, int col0,
                     int Mreal, int Kpad,
                     unsigned short* Asb, unsigned short* Bsb)
{
    const int tid  = threadIdx.x;
    const int lane = tid & 63;
    const int wv   = tid >> 6;        // 0..3
    const int wr   = wv >> 1;         // wave row half
    const int wc   = wv & 1;          // wave col half
    const int l15  = lane & 15;
    const int lk   = lane >> 4;
    const int sub  = lane >> 3;       // staging sub-row 0..7
    const int schk = lane & 7;        // staging 16B chunk 0..7
    const int nt   = Kpad >> 6;

    auto stage = [&](int row0, int k0) {
#pragma unroll
        for (int j = 0; j < 4; ++j) {
            const int ii = wv * 4 + j;
            const int r  = ii * 8 + sub;
            const int cg = schk ^ (r & 7);
            gload16(A + (size_t)(row0 + r) * Kpad + k0 + cg * 8, Asb + ii * 512);
        }
#pragma unroll
        for (int j = 0; j < 4; ++j) {
            const int ii = wv * 4 + j;
            const int r  = ii * 8 + sub;
            const int cg = schk ^ (r & 7);
            gload16(BT + (size_t)(col0 + r) * Kpad + k0 + cg * 8, Bsb + ii * 512);
        }
    };

    f32x4 acc[4][4];
#pragma unroll
    for (int i = 0; i < 4; ++i)
#pragma unroll
        for (int j = 0; j < 4; ++j) acc[i][j] = (f32x4){0.f, 0.f, 0.f, 0.f};

    stage(g0 * 128, 0);
    __syncthreads();

    for (int t = 0; t < T; ++t) {
        const int g = g0 + t * 8;
        if (g >= Mtiles) break;       // only reached when stage was skipped
        const int row0 = g * 128;
        for (int kt = 0; kt < nt; ++kt) {
#pragma unroll
            for (int ks = 0; ks < 2; ++ks) {
                bf16x8 af[4], bfg[4];
#pragma unroll
                for (int mi = 0; mi < 4; ++mi) {
                    const int r = wr * 64 + mi * 16 + l15;
                    const int c = ks * 4 + lk;
                    af[mi] = *(const bf16x8*)((const char*)Asb
                              + r * 128 + ((c ^ (r & 7)) << 4));
                }
#pragma unroll
                for (int ni = 0; ni < 4; ++ni) {
                    const int r = wc * 64 + ni * 16 + l15;
                    const int c = ks * 4 + lk;
                    bfg[ni] = *(const bf16x8*)((const char*)Bsb
                               + r * 128 + ((c ^ (r & 7)) << 4));
                }
#pragma unroll
                for (int mi = 0; mi < 4; ++mi)
#pragma unroll
                    for (int ni = 0; ni < 4; ++ni)
                        acc[mi][ni] = __builtin_amdgcn_mfma_f32_16x16x32_bf16(
                            af[mi], bfg[ni], acc[mi][ni], 0, 0, 0);
            }
            __syncthreads();          // all LDS reads complete

            if (kt != nt - 1) {
                stage(row0, (kt + 1) << 6);
            } else {
                const int gn = g + 8;
                if (t + 1 < T && gn < Mtiles) stage(gn * 128, 0);
                // epilogue for tile g overlaps the stage loads
#pragma unroll
                for (int mi = 0; mi < 4; ++mi) {
#pragma unroll
                    for (int r = 0; r < 4; ++r) {
                        const int row = row0 + wr * 64 + mi * 16 + lk * 4 + r;
                        if (row < Mreal) {
#pragma unroll
                            for (int ni = 0; ni < 4; ++ni) {
                                const int col = col0 + wc * 64 + ni * 16 + l15;
                                float o = acc[mi][ni][r];
                                if (FLAGS & 2) o += bias[col];
                                if (FLAGS & 1) o = fmaxf(o, 0.f);
                                if (FLAGS & 4) o += bf2f(res[(size_t)row * HID + col]);
                                if (CBF) ((unsigned short*)Cv)[(size_t)row * HID + col] = f2bf(o);
                                else     ((float*)Cv)[(size_t)row * HID + col] = o;
                            }
                        }
                    }
                }
#pragma unroll
                for (int i = 0; i < 4; ++i)
#pragma unroll
                    for (int j = 0; j < 4; ++j) acc[i][j] = (f32x4){0.f, 0.f, 0.f, 0.f};
            }
            __syncthreads();          // drain stage (vmcnt 0) -> buffer ready
        }
    }
}

// generic (2 members = col halves): x -> xcd = x&7, y = x>>3, m = y&1, c = y>>1
template<int FLAGS, bool CBF>
__global__ __launch_bounds__(256, 4)
void gemm128(const unsigned short* __restrict__ A,
             const unsigned short* __restrict__ BT,
             const float* __restrict__ bias,
             const unsigned short* __restrict__ res,
             void* __restrict__ Cv, int Mtiles, int Mreal, int Kpad, int T)
{
    __shared__ alignas(16) unsigned short Asb[128 * 64];
    __shared__ alignas(16) unsigned short Bsb[128 * 64];
    const int x   = blockIdx.x;
    const int xcd = x & 7;
    const int y   = x >> 3;
    const int m   = y & 1;
    const int c   = y >> 1;
    const int g0  = c * T * 8 + xcd;
    if (g0 >= Mtiles) return;
    gemm128_mt_core<FLAGS, CBF>(A, BT, bias, res, Cv, g0, T, Mtiles, m * 128,
                                Mreal, Kpad, Asb, Bsb);
}

// qkv (6 members = 3 proj x 2 col halves), same-XCD A sharing per tile [T1]
__global__ __launch_bounds__(256, 4)
void gemm128_qkv(const unsigned short* __restrict__ A,
                 const unsigned short* __restrict__ BTq,
                 const unsigned short* __restrict__ BTk,
                 const unsigned short* __restrict__ BTv,
                 unsigned short* __restrict__ Cq,
                 unsigned short* __restrict__ Ck,
                 unsigned short* __restrict__ Cvp, int Mtiles, int T)
{
    __shared__ alignas(16) unsigned short Asb[128 * 64];
    __shared__ alignas(16) unsigned short Bsb[128 * 64];
    const int x   = blockIdx.x;
    const int xcd = x & 7;
    const int y   = x >> 3;
    const int m   = y % 6;
    const int c   = y / 6;
    const int g0  = c * T * 8 + xcd;
    if (g0 >= Mtiles) return;
    const int proj = m >> 1;
    const int ch   = m & 1;
    const unsigned short* BT = (proj == 0) ? BTq : (proj == 1) ? BTk : BTv;
    unsigned short*       C  = (proj == 0) ? Cq  : (proj == 1) ? Ck  : Cvp;
    gemm128_mt_core<0, true>(A, BT, nullptr, nullptr, C, g0, T, Mtiles,
                             ch * 128, NE, 256, Asb, Bsb);
}

// ---------------------------------------------------------------------------
__global__ __launch_bounds__(256)
void wconv(const float* __restrict__ W, unsigned short* __restrict__ BT,
           int Kreal, int Kpad)
{
    const int idx = blockIdx.x * 256 + threadIdx.x;
    const int n = idx / Kpad, kp = idx - n * Kpad;
    float v = (kp < Kreal) ? W[(size_t)kp * HID + n] : 0.f;
    BT[idx] = f2bf(v);
}

__global__ __launch_bounds__(256)
void wconv10(const float* __restrict__ Wq, const float* __restrict__ Wk,
             const float* __restrict__ Wv, const float* __restrict__ L1w,
             const float* __restrict__ L2w, unsigned short* __restrict__ outbase)
{
    const int y = blockIdx.y;
    const int l = y / 5, which = y - l * 5;
    const float* src;
    switch (which) {
        case 0: src = Wq;  break;
        case 1: src = Wk;  break;
        case 2: src = Wv;  break;
        case 3: src = L1w; break;
        default: src = L2w; break;
    }
    src += (size_t)l * 65536;
    const int idx = blockIdx.x * 256 + threadIdx.x;
    const int n = idx >> 8, kp = idx & 255;
    outbase[(size_t)y * 65536 + idx] = f2bf(src[(size_t)kp * HID + n]);
}

// ---------------------------------------------------------------------------
__global__ __launch_bounds__(256)
void build_initA(const float* __restrict__ atom, const float* __restrict__ edge,
                 const int* __restrict__ src, unsigned short* __restrict__ out)
{
    const long total = (long)NE * 192;
    long idx = (long)blockIdx.x * blockDim.x + threadIdx.x;
    if (idx >= total) return;
    const int e = (int)(idx / 192);
    const int c = (int)(idx - (long)e * 192);
    float v = 0.f;
    if (c < 133)      v = atom[(size_t)src[e] * 133 + c];
    else if (c < 147) v = edge[(size_t)e * 14 + (c - 133)];
    out[idx] = f2bf(v);
}

__global__ __launch_bounds__(256)
void build_finalA(const float* __restrict__ atom, const float* __restrict__ fsum,
                  unsigned short* __restrict__ out)
{
    const long total = (long)NNP * 448;
    long idx = (long)blockIdx.x * blockDim.x + threadIdx.x;
    if (idx >= total) return;
    const int n = (int)(idx / 448);
    const int c = (int)(idx - (long)n * 448);
    float v = 0.f;
    if (n < NN) {
        if (c < 133)      v = atom[(size_t)n * 133 + c];
        else if (c < 389) v = fsum[(size_t)n * 256 + (c - 133)];
    }
    out[idx] = f2bf(v);
}

// ---------------------------------------------------------------------------
// Combined CSR build: one counts/offsets array covering triplet keys [0,NE)
// and node keys [NE, NE+NN). One scan chain. plist payload:
//   [0, NT)     : kj value per triplet slot
//   [NT, NT+NE) : edge id per node slot
// ---------------------------------------------------------------------------
__global__ __launch_bounds__(256)
void count_keys(const int* __restrict__ key, int n, int nkeys, int* __restrict__ cnt)
{
    const int i = blockIdx.x * 256 + threadIdx.x;
    if (i < n) {
        const int kk = key[i];
        if ((unsigned)kk < (unsigned)nkeys) atomicAdd(&cnt[kk], 1);
    }
}

__global__ __launch_bounds__(256)
void fill_trip(const int* __restrict__ idx_ji, const int* __restrict__ idx_kj,
               int* __restrict__ cur, int* __restrict__ plist)
{
    const int i = blockIdx.x * 256 + threadIdx.x;
    if (i >= NT) return;
    const int kk = idx_ji[i];
    if ((unsigned)kk >= (unsigned)NE) return;
    const int pos = atomicAdd(&cur[kk], 1);
    if ((unsigned)pos < (unsigned)NT) plist[pos] = idx_kj[i];
}

__global__ __launch_bounds__(256)
void fill_node(const int* __restrict__ dst, int* __restrict__ cur,
               int* __restrict__ plist)
{
    const int i = blockIdx.x * 256 + threadIdx.x;
    if (i >= NE) return;
    const int kk = dst[i];
    if ((unsigned)kk >= (unsigned)NN) return;
    const int pos = atomicAdd(&cur[NE + kk], 1);
    if ((unsigned)pos < (unsigned)(NT + NE)) plist[pos] = i;
}

// per-block (2048 elems, 8/thread) exclusive scan; partials out (<=256 blocks)
__global__ __launch_bounds__(256)
void scan1(const int* __restrict__ in, int n, int* __restrict__ excl,
           int* __restrict__ part)
{
    __shared__ int sh[256];
    const int t = threadIdx.x;
    const int base = blockIdx.x * 2048 + t * 8;
    int v[8]; int s = 0;
#pragma unroll
    for (int j = 0; j < 8; ++j) { v[j] = (base + j < n) ? in[base + j] : 0; s += v[j]; }
    sh[t] = s; __syncthreads();
    for (int off = 1; off < 256; off <<= 1) {
        int x = (t >= off) ? sh[t - off] : 0;
        __syncthreads();
        sh[t] += x;
        __syncthreads();
    }
    int ex = sh[t] - s;
#pragma unroll
    for (int j = 0; j < 8; ++j) { if (base + j < n) excl[base + j] = ex; ex += v[j]; }
    if (t == 255) part[blockIdx.x] = sh[255];
}

__global__ __launch_bounds__(256)
void scan2(int* __restrict__ part, int nparts)
{
    __shared__ int sh[256];
    const int t = threadIdx.x;
    const int v = (t < nparts) ? part[t] : 0;
    sh[t] = v; __syncthreads();
    for (int off = 1; off < 256; off <<= 1) {
        int x = (t >= off) ? sh[t - off] : 0;
        __syncthreads();
        sh[t] += x;
        __syncthreads();
    }
    if (t < nparts) part[t] = sh[t] - v;
}

// offs[i] = cur[i] = excl[i] + part[i/2048]; offs[n] = total.
// counts/cur alias intentionally (non-restrict); read c before write.
__global__ __launch_bounds__(256)
void scan3(const int* __restrict__ excl, const int* __restrict__ part,
           const int* counts, int n, int* __restrict__ offs, int* cur)
{
    const int i = blockIdx.x * 256 + threadIdx.x;
    if (i >= n) return;
    const int v = excl[i] + part[i >> 11];
    const int c = counts[i];
    offs[i] = v;
    cur[i] = v;
    if (i == n - 1) offs[n] = v + c;
}

// ---------------------------------------------------------------------------
// Fused attention gather: 32 lanes per edge (2 edges/wave), bf16x8 loads,
// pre-resolved kj list with one-deep prefetch.
// ---------------------------------------------------------------------------
__global__ __launch_bounds__(256)
void gather_v(const unsigned short* __restrict__ q, const unsigned short* __restrict__ k,
              const unsigned short* __restrict__ v,
              const int* __restrict__ toff, const int* __restrict__ tkj,
              unsigned short* __restrict__ vc)
{
    const long gtid = (long)blockIdx.x * blockDim.x + threadIdx.x;
    const int w    = (int)(gtid >> 5);
    const int lane = threadIdx.x & 31;
    if (w >= NE) return;
    int beg = toff[w], end = toff[w + 1];
    if (beg < 0) beg = 0;
    if (end > NT) end = NT;

    const bf16x8 kv = *(const bf16x8*)(k + (size_t)w * HID + lane * 8);
    float kf[8];
#pragma unroll
    for (int j = 0; j < 8; ++j) kf[j] = bf2f((unsigned short)kv[j]);

    float av[8];
#pragma unroll
    for (int j = 0; j < 8; ++j) av[j] = 0.f;
    float den = 0.f;

    int kj_next = (beg < end) ? tkj[beg] : -1;
    for (int p = beg; p < end; ++p) {
        const int kj = kj_next;
        if (p + 1 < end) kj_next = tkj[p + 1];
        if ((unsigned)kj >= (unsigned)NE) continue;
        const bf16x8 qv = *(const bf16x8*)(q + (size_t)kj * HID + lane * 8);
        float s = 0.f;
#pragma unroll
        for (int j = 0; j < 8; ++j) s += bf2f((unsigned short)qv[j]) * kf[j];
        s += __shfl_xor(s, 1);
        s += __shfl_xor(s, 2);
        const float lr = (s > 0.f) ? s : 0.2f * s;
        const float a  = __expf(lr);
        den += a;
        const bf16x8 vv = *(const bf16x8*)(v + (size_t)kj * HID + lane * 8);
#pragma unroll
        for (int j = 0; j < 8; ++j) av[j] += a * bf2f((unsigned short)vv[j]);
    }
    const float inv = (den != 0.f) ? 1.f / den : 0.f;
    bf16x8 o;
#pragma unroll
    for (int j = 0; j < 8; ++j) o[j] = (short)f2bf(av[j] * inv);
    *(bf16x8*)(vc + (size_t)w * HID + lane * 8) = o;
}

// ---------------------------------------------------------------------------
// edge->node gather: 32 lanes per node, bf16x8 loads, f32 out.
// noff points at the node region (offs+NE); positions absolute in plist.
// ---------------------------------------------------------------------------
__global__ __launch_bounds__(256)
void gather_node(const unsigned short* __restrict__ feats,
                 const int* __restrict__ noff, const int* __restrict__ nlist,
                 float* __restrict__ fsum)
{
    const long gtid = (long)blockIdx.x * blockDim.x + threadIdx.x;
    const int w    = (int)(gtid >> 5);
    const int lane = threadIdx.x & 31;
    if (w >= NN) return;
    int beg = noff[w], end = noff[w + 1];
    if (beg < 0) beg = 0;
    if (end > NT + NE) end = NT + NE;
    float av[8];
#pragma unroll
    for (int j = 0; j < 8; ++j) av[j] = 0.f;
    int e_next = (beg < end) ? nlist[beg] : -1;
    for (int p = beg; p < end; ++p) {
        const int e = e_next;
        if (p + 1 < end) e_next = nlist[p + 1];
        if ((unsigned)e >= (unsigned)NE) continue;
        const bf16x8 f = *(const bf16x8*)(feats + (size_t)e * HID + lane * 8);
#pragma unroll
        for (int j = 0; j < 8; ++j) av[j] += bf2f((unsigned short)f[j]);
    }
    float4 o0 = make_float4(av[0], av[1], av[2], av[3]);
    float4 o1 = make_float4(av[4], av[5], av[6], av[7]);
    float* out = fsum + (size_t)w * HID + lane * 8;
    *reinterpret_cast<float4*>(out)     = o0;
    *reinterpret_cast<float4*>(out + 4) = o1;
}

// ---------------------------------------------------------------------------
extern "C" void kernel_launch(void* const* d_in, const int* in_sizes, int n_in,
                              void* d_out, int out_size, void* d_ws, size_t ws_size,
                              hipStream_t stream)
{
    const float* atom = (const float*)d_in[0];
    const float* edge = (const float*)d_in[1];
    const float* W_i  = (const float*)d_in[2];
    const float* Wq   = (const float*)d_in[3];
    const float* Wk   = (const float*)d_in[4];
    const float* Wv   = (const float*)d_in[5];
    const float* L1w  = (const float*)d_in[6];
    const float* L1b  = (const float*)d_in[7];
    const float* L2w  = (const float*)d_in[8];
    const float* L2b  = (const float*)d_in[9];
    const float* Wo   = (const float*)d_in[10];
    const float* bo   = (const float*)d_in[11];
    const int* src    = (const int*)d_in[12];
    const int* dst    = (const int*)d_in[13];
    const int* idx_kj = (const int*)d_in[14];
    const int* idx_ji = (const int*)d_in[15];

    const size_t RB = (size_t)NE * HID * 2;   // 102,400,000 B
    char* ws = (char*)d_ws;
    unsigned short* feats = (unsigned short*)(ws);
    unsigned short* qb    = (unsigned short*)(ws + RB);
    unsigned short* kb    = (unsigned short*)(ws + 2 * RB);
    unsigned short* vb    = (unsigned short*)d_out;     // NE*256 bf16 == d_out bytes
    unsigned short* vc    = feats;                      // v_clone overlays feats
    unsigned short* initA = qb;                         // NEP*192 bf16 = 76.8MB < RB
    unsigned short* h1    = kb;
    float*          fsum  = (float*)(ws + RB);          // NN*256 f32 == RB
    unsigned short* finalA = kb;                        // NNP*448 bf16 = 89.7MB < RB

    const int NK = NE + NN;                 // combined key count
    char* p = ws + 3 * RB;
    int* offs     = (int*)p; p += ((size_t)NK + 16) * 4;
    int* cur      = (int*)p; p += ((size_t)NK + 16) * 4;
    int* plist    = (int*)p; p += (size_t)(NT + NE) * 4;
    int* tmp_excl = (int*)p; p += ((size_t)NK + 16) * 4;
    int* partials = (int*)p; p += 1024;
    unsigned short* wiT = (unsigned short*)p; p += (size_t)256 * 192 * 2;
    unsigned short* wT0 = (unsigned short*)p; p += (size_t)10 * 65536 * 2;
    unsigned short* woT = (unsigned short*)p; p += (size_t)256 * 448 * 2;
    const size_t NEEDED = (size_t)(p - ws);
    if (ws_size < NEEDED) return;
    auto wT = [&](int i) { return wT0 + (size_t)i * 65536; };

    const int MT_E  = NEP / 128;                 // 1563 M-tiles (edge GEMMs)
    const int MT_N  = NNP / 128;                 // 782 (final GEMM)
    const int NPARTS = (NK + 2047) / 2048;       // 147 <= 256

    // multi-tile grid sizing: jmax = tiles per xcd, chunks of T tiles
    const int JE = (MT_E + 7) / 8;               // 196
    const int JN = (MT_N + 7) / 8;               // 98
    const int T_QKV = 4, T_G = 2;
    const int GRID_QKV = 8 * 6 * ((JE + T_QKV - 1) / T_QKV);   // 2352
    const int GRID_E   = 8 * 2 * ((JE + T_G - 1) / T_G);       // 1568
    const int GRID_N   = 8 * 2 * ((JN + T_G - 1) / T_G);       // 784

    // ---- weight convert/transpose/pad (bf16) ----
    wconv<<<192, 256, 0, stream>>>(W_i, wiT, 147, 192);
    wconv10<<<dim3(256, 10), 256, 0, stream>>>(Wq, Wk, Wv, L1w, L2w, wT0);
    wconv<<<448, 256, 0, stream>>>(Wo, woT, 389, 448);

    // ---- combined CSR build ----
    hipMemsetAsync(cur, 0, (size_t)NK * 4, stream);
    count_keys<<<(NT + 255) / 256, 256, 0, stream>>>(idx_ji, NT, NE, cur);
    count_keys<<<(NE + 255) / 256, 256, 0, stream>>>(dst, NE, NN, cur + NE);
    scan1<<<NPARTS, 256, 0, stream>>>(cur, NK, tmp_excl, partials);
    scan2<<<1, 256, 0, stream>>>(partials, NPARTS);
    scan3<<<(NK + 255) / 256, 256, 0, stream>>>(tmp_excl, partials, cur, NK, offs, cur);
    fill_trip<<<(NT + 255) / 256, 256, 0, stream>>>(idx_ji, idx_kj, cur, plist);
    fill_node<<<(NE + 255) / 256, 256, 0, stream>>>(dst, cur, plist);

    // ---- init: feats = relu(concat(atom[src], edge) @ W_i) ----
    {
        const long total = (long)NE * 192;
        build_initA<<<(int)((total + 255) / 256), 256, 0, stream>>>(atom, edge, src, initA);
    }
    gemm128<1, true><<<GRID_E, 256, 0, stream>>>(initA, wiT, nullptr, nullptr,
                                                 feats, MT_E, NE, 192, T_G);

    // ---- 2 attention layers ----
    for (int l = 0; l < 2; ++l) {
        const float* l1b = L1b + (size_t)l * 256;
        const float* l2b = L2b + (size_t)l * 256;

        gemm128_qkv<<<GRID_QKV, 256, 0, stream>>>(
            feats, wT(l * 5 + 0), wT(l * 5 + 1), wT(l * 5 + 2), qb, kb, vb,
            MT_E, T_QKV);

        gather_v<<<(NE * 32) / 256, 256, 0, stream>>>(qb, kb, vb, offs, plist, vc);

        // h1 = relu(vc @ L1 + b1); feats = v + relu(h1 @ L2 + b2)
        gemm128<3, true><<<GRID_E, 256, 0, stream>>>(vc, wT(l * 5 + 3), l1b,
                                                     nullptr, h1, MT_E, NE, 256, T_G);
        gemm128<7, true><<<GRID_E, 256, 0, stream>>>(h1, wT(l * 5 + 4), l2b,
                                                     vb, feats, MT_E, NE, 256, T_G);
    }

    // ---- edge -> node gather, final projection ----
    gather_node<<<(NN * 32) / 256, 256, 0, stream>>>(feats, offs + NE, plist, fsum);
    {
        const long total = (long)NNP * 448;
        build_finalA<<<(int)((total + 255) / 256), 256, 0, stream>>>(atom, fsum, finalA);
    }
    gemm128<3, false><<<GRID_N, 256, 0, stream>>>(finalA, woT, bo, nullptr,
                                                  d_out, MT_N, NN, 448, T_G);
}

// Round 15
// 1207.510 us; speedup vs baseline: 1.7260x; 1.7260x over previous
//
#include <hip/hip_runtime.h>
#include <stdint.h>

#define NN 100000
#define NNP 100096          // NN padded to multiple of 128
#define NE 200000
#define NEP 200064          // NE padded to multiple of 128
#define NT 600000
#define HID 256

typedef __attribute__((ext_vector_type(8))) short bf16x8;
typedef __attribute__((ext_vector_type(4))) float f32x4;

__device__ __forceinline__ float bf2f(unsigned short u) {
    union { unsigned int i; float f; } x; x.i = ((unsigned int)u) << 16; return x.f;
}
__device__ __forceinline__ unsigned short f2bf(float f) {
    union { float f; unsigned int i; } x; x.f = f;
    unsigned int r = (x.i + 0x7FFFu + ((x.i >> 16) & 1u)) >> 16;
    return (unsigned short)r;
}

// async global->LDS, 16B per lane; LDS dest = wave-uniform base + lane*16
__device__ __forceinline__ void gload16(const void* g, void* l) {
    __builtin_amdgcn_global_load_lds(
        (const __attribute__((address_space(1))) void*)g,
        (__attribute__((address_space(3))) void*)l, 16, 0, 0);
}

// ---------------------------------------------------------------------------
// m97-style GEMM core (round-13 proven form — DO NOT restructure):
// 4 waves (2x2), wave tile 64x64, BK=64, 32 KB LDS, 2-barrier loop,
// gload_lds staging, rule-21 swizzle pair.
// FAILED RESTRUCTURES (counter-evidenced): C^T epilogue swap (r12, -7%);
// multi-tile persistent loop (r14: acc spilled, VGPR 64, WRITE x3.3,
// MfmaUtil 3%); (256,5)/(512,6) bounds (r8/r10 spills). Register budget:
// 512 wave-regs/SIMD unified VGPR+AGPR; 64 acc + ~60 addr = 124; (256,4)
// caps 128 — zero slack for extra control flow.
// ---------------------------------------------------------------------------
template<int FLAGS, bool CBF>
__device__ __forceinline__
void gemm128_core(const unsigned short* __restrict__ A,
                  const unsigned short* __restrict__ BT,
                  const float* __restrict__ bias,
                  const unsigned short* __restrict__ res,
                  void* __restrict__ Cv, int row0, int col0,
                  int Mreal, int Kpad,
                  unsigned short* Asb, unsigned short* Bsb)
{
    const int t    = threadIdx.x;
    const int lane = t & 63;
    const int wv   = t >> 6;          // 0..3
    const int wr   = wv >> 1;         // wave row half
    const int wc   = wv & 1;          // wave col half
    const int l15  = lane & 15;
    const int lk   = lane >> 4;
    const int sub  = lane >> 3;       // staging sub-row 0..7
    const int schk = lane & 7;        // staging 16B chunk 0..7

    f32x4 acc[4][4];
#pragma unroll
    for (int i = 0; i < 4; ++i)
#pragma unroll
        for (int j = 0; j < 4; ++j) acc[i][j] = (f32x4){0.f, 0.f, 0.f, 0.f};

    const int nt = Kpad >> 6;
    for (int kt = 0; kt < nt; ++kt) {
        const int k0 = kt << 6;
#pragma unroll
        for (int j = 0; j < 4; ++j) {
            const int ii = wv * 4 + j;
            const int r  = ii * 8 + sub;
            const int cg = schk ^ (r & 7);
            gload16(A + (size_t)(row0 + r) * Kpad + k0 + cg * 8, Asb + ii * 512);
        }
#pragma unroll
        for (int j = 0; j < 4; ++j) {
            const int ii = wv * 4 + j;
            const int r  = ii * 8 + sub;
            const int cg = schk ^ (r & 7);
            gload16(BT + (size_t)(col0 + r) * Kpad + k0 + cg * 8, Bsb + ii * 512);
        }
        __syncthreads();     // compiler drains vmcnt before s_barrier
#pragma unroll
        for (int ks = 0; ks < 2; ++ks) {
            bf16x8 af[4], bfg[4];
#pragma unroll
            for (int mi = 0; mi < 4; ++mi) {
                const int r = wr * 64 + mi * 16 + l15;
                const int c = ks * 4 + lk;
                af[mi] = *(const bf16x8*)((const char*)Asb
                          + r * 128 + ((c ^ (r & 7)) << 4));
            }
#pragma unroll
            for (int ni = 0; ni < 4; ++ni) {
                const int r = wc * 64 + ni * 16 + l15;
                const int c = ks * 4 + lk;
                bfg[ni] = *(const bf16x8*)((const char*)Bsb
                           + r * 128 + ((c ^ (r & 7)) << 4));
            }
#pragma unroll
            for (int mi = 0; mi < 4; ++mi)
#pragma unroll
                for (int ni = 0; ni < 4; ++ni)
                    acc[mi][ni] = __builtin_amdgcn_mfma_f32_16x16x32_bf16(
                        af[mi], bfg[ni], acc[mi][ni], 0, 0, 0);
        }
        __syncthreads();     // reads done before next stage overwrites
    }

    // epilogue: D col=l&15, row=(l>>4)*4+reg  [m89-verified]
#pragma unroll
    for (int mi = 0; mi < 4; ++mi) {
#pragma unroll
        for (int r = 0; r < 4; ++r) {
            const int row = row0 + wr * 64 + mi * 16 + lk * 4 + r;
            if (row >= Mreal) continue;
#pragma unroll
            for (int ni = 0; ni < 4; ++ni) {
                const int col = col0 + wc * 64 + ni * 16 + l15;
                float o = acc[mi][ni][r];
                if (FLAGS & 2) o += bias[col];
                if (FLAGS & 1) o = fmaxf(o, 0.f);
                if (FLAGS & 4) o += bf2f(res[(size_t)row * HID + col]);
                if (CBF) ((unsigned short*)Cv)[(size_t)row * HID + col] = f2bf(o);
                else     ((float*)Cv)[(size_t)row * HID + col] = o;
            }
        }
    }
}

// XCD-aware swizzle [T1]: x = xcd + 8*(member + MEMBERS*local_group).
template<int FLAGS, bool CBF>
__global__ __launch_bounds__(256, 4)
void gemm128(const unsigned short* __restrict__ A,
             const unsigned short* __restrict__ BT,
             const float* __restrict__ bias,
             const unsigned short* __restrict__ res,
             void* __restrict__ Cv, int Mtiles, int Mreal, int Kpad)
{
    __shared__ alignas(16) unsigned short Asb[128 * 64];
    __shared__ alignas(16) unsigned short Bsb[128 * 64];
    const int x   = blockIdx.x;
    const int xcd = x & 7;
    const int ii  = x >> 3;
    const int g   = (ii >> 1) * 8 + xcd;     // tile-group = M tile
    const int ch  = ii & 1;
    if (g >= Mtiles) return;
    gemm128_core<FLAGS, CBF>(A, BT, bias, res, Cv, g * 128, ch * 128,
                             Mreal, Kpad, Asb, Bsb);
}

// qkv: grid.x = Mtiles8 * 6; 6 members (3 proj x 2 halves) share one A tile
__global__ __launch_bounds__(256, 4)
void gemm128_qkv(const unsigned short* __restrict__ A,
                 const unsigned short* __restrict__ BTq,
                 const unsigned short* __restrict__ BTk,
                 const unsigned short* __restrict__ BTv,
                 unsigned short* __restrict__ Cq,
                 unsigned short* __restrict__ Ck,
                 unsigned short* __restrict__ Cvp, int Mtiles)
{
    __shared__ alignas(16) unsigned short Asb[128 * 64];
    __shared__ alignas(16) unsigned short Bsb[128 * 64];
    const int x   = blockIdx.x;
    const int xcd = x & 7;
    const int ii  = x >> 3;
    const int g   = (ii / 6) * 8 + xcd;
    const int j   = ii % 6;
    if (g >= Mtiles) return;
    const int proj = j >> 1;
    const int ch   = j & 1;
    const unsigned short* BT = (proj == 0) ? BTq : (proj == 1) ? BTk : BTv;
    unsigned short*       C  = (proj == 0) ? Cq  : (proj == 1) ? Ck  : Cvp;
    gemm128_core<0, true>(A, BT, nullptr, nullptr, C, g * 128, ch * 128,
                          NE, 256, Asb, Bsb);
}

// ---------------------------------------------------------------------------
__global__ __launch_bounds__(256)
void wconv(const float* __restrict__ W, unsigned short* __restrict__ BT,
           int Kreal, int Kpad)
{
    const int idx = blockIdx.x * 256 + threadIdx.x;
    const int n = idx / Kpad, kp = idx - n * Kpad;
    float v = (kp < Kreal) ? W[(size_t)kp * HID + n] : 0.f;
    BT[idx] = f2bf(v);
}

// Wo with PERMUTED K: kp<256 -> Wo row 133+kp (fsum part); 256<=kp<389 ->
// Wo row kp-256 (atom part); else 0. Must match finalA column layout.
__global__ __launch_bounds__(256)
void wconv_wo(const float* __restrict__ W, unsigned short* __restrict__ BT)
{
    const int idx = blockIdx.x * 256 + threadIdx.x;   // grid 448 blocks
    const int n = idx / 448, kp = idx - n * 448;
    float v = 0.f;
    if (kp < 256)      v = W[(size_t)(133 + kp) * HID + n];
    else if (kp < 389) v = W[(size_t)(kp - 256) * HID + n];
    BT[idx] = f2bf(v);
}

__global__ __launch_bounds__(256)
void wconv10(const float* __restrict__ Wq, const float* __restrict__ Wk,
             const float* __restrict__ Wv, const float* __restrict__ L1w,
             const float* __restrict__ L2w, unsigned short* __restrict__ outbase)
{
    const int y = blockIdx.y;
    const int l = y / 5, which = y - l * 5;
    const float* src;
    switch (which) {
        case 0: src = Wq;  break;
        case 1: src = Wk;  break;
        case 2: src = Wv;  break;
        case 3: src = L1w; break;
        default: src = L2w; break;
    }
    src += (size_t)l * 65536;
    const int idx = blockIdx.x * 256 + threadIdx.x;
    const int n = idx >> 8, kp = idx & 255;
    outbase[(size_t)y * 65536 + idx] = f2bf(src[(size_t)kp * HID + n]);
}

// ---------------------------------------------------------------------------
__global__ __launch_bounds__(256)
void build_initA(const float* __restrict__ atom, const float* __restrict__ edge,
                 const int* __restrict__ src, unsigned short* __restrict__ out)
{
    const long total = (long)NE * 192;
    long idx = (long)blockIdx.x * blockDim.x + threadIdx.x;
    if (idx >= total) return;
    const int e = (int)(idx / 192);
    const int c = (int)(idx - (long)e * 192);
    float v = 0.f;
    if (c < 133)      v = atom[(size_t)src[e] * 133 + c];
    else if (c < 147) v = edge[(size_t)e * 14 + (c - 133)];
    out[idx] = f2bf(v);
}

// fill finalA atom columns [256,389) and zero pad [389,448) for rows < NN.
// (fsum columns [0,256) are written directly by gather_node; pad rows by memset)
__global__ __launch_bounds__(256)
void build_final_atom(const float* __restrict__ atom, unsigned short* __restrict__ out)
{
    const long total = (long)NN * 192;
    long idx = (long)blockIdx.x * blockDim.x + threadIdx.x;
    if (idx >= total) return;
    const int n = (int)(idx / 192);
    const int c = (int)(idx - (long)n * 192);          // 0..191 -> col 256+c
    float v = (c < 133) ? atom[(size_t)n * 133 + c] : 0.f;
    out[(size_t)n * 448 + 256 + c] = f2bf(v);
}

// ---------------------------------------------------------------------------
// Combined CSR build: counts/offsets over triplet keys [0,NE) + node keys
// [NE, NE+NN); one scan chain. plist: [0,NT) kj per triplet slot;
// [NT,NT+NE) edge id per node slot.
// ---------------------------------------------------------------------------
__global__ __launch_bounds__(256)
void count_keys(const int* __restrict__ key, int n, int nkeys, int* __restrict__ cnt)
{
    const int i = blockIdx.x * 256 + threadIdx.x;
    if (i < n) {
        const int kk = key[i];
        if ((unsigned)kk < (unsigned)nkeys) atomicAdd(&cnt[kk], 1);
    }
}

__global__ __launch_bounds__(256)
void fill_trip(const int* __restrict__ idx_ji, const int* __restrict__ idx_kj,
               int* __restrict__ cur, int* __restrict__ plist)
{
    const int i = blockIdx.x * 256 + threadIdx.x;
    if (i >= NT) return;
    const int kk = idx_ji[i];
    if ((unsigned)kk >= (unsigned)NE) return;
    const int pos = atomicAdd(&cur[kk], 1);
    if ((unsigned)pos < (unsigned)NT) plist[pos] = idx_kj[i];
}

__global__ __launch_bounds__(256)
void fill_node(const int* __restrict__ dst, int* __restrict__ cur,
               int* __restrict__ plist)
{
    const int i = blockIdx.x * 256 + threadIdx.x;
    if (i >= NE) return;
    const int kk = dst[i];
    if ((unsigned)kk >= (unsigned)NN) return;
    const int pos = atomicAdd(&cur[NE + kk], 1);
    if ((unsigned)pos < (unsigned)(NT + NE)) plist[pos] = i;
}

// per-block (2048 elems, 8/thread) exclusive scan; partials out (<=256 blocks)
__global__ __launch_bounds__(256)
void scan1(const int* __restrict__ in, int n, int* __restrict__ excl,
           int* __restrict__ part)
{
    __shared__ int sh[256];
    const int t = threadIdx.x;
    const int base = blockIdx.x * 2048 + t * 8;
    int v[8]; int s = 0;
#pragma unroll
    for (int j = 0; j < 8; ++j) { v[j] = (base + j < n) ? in[base + j] : 0; s += v[j]; }
    sh[t] = s; __syncthreads();
    for (int off = 1; off < 256; off <<= 1) {
        int x = (t >= off) ? sh[t - off] : 0;
        __syncthreads();
        sh[t] += x;
        __syncthreads();
    }
    int ex = sh[t] - s;
#pragma unroll
    for (int j = 0; j < 8; ++j) { if (base + j < n) excl[base + j] = ex; ex += v[j]; }
    if (t == 255) part[blockIdx.x] = sh[255];
}

__global__ __launch_bounds__(256)
void scan2(int* __restrict__ part, int nparts)
{
    __shared__ int sh[256];
    const int t = threadIdx.x;
    const int v = (t < nparts) ? part[t] : 0;
    sh[t] = v; __syncthreads();
    for (int off = 1; off < 256; off <<= 1) {
        int x = (t >= off) ? sh[t - off] : 0;
        __syncthreads();
        sh[t] += x;
        __syncthreads();
    }
    if (t < nparts) part[t] = sh[t] - v;
}

__global__ __launch_bounds__(256)
void scan3(const int* __restrict__ excl, const int* __restrict__ part,
           const int* counts, int n, int* __restrict__ offs, int* cur)
{
    const int i = blockIdx.x * 256 + threadIdx.x;
    if (i >= n) return;
    const int v = excl[i] + part[i >> 11];
    const int c = counts[i];
    offs[i] = v;
    cur[i] = v;
    if (i == n - 1) offs[n] = v + c;
}

// ---------------------------------------------------------------------------
// Fused attention gather: 32 lanes per edge, bf16x8 loads, pre-resolved kj.
// ---------------------------------------------------------------------------
__global__ __launch_bounds__(256)
void gather_v(const unsigned short* __restrict__ q, const unsigned short* __restrict__ k,
              const unsigned short* __restrict__ v,
              const int* __restrict__ toff, const int* __restrict__ tkj,
              unsigned short* __restrict__ vc)
{
    const long gtid = (long)blockIdx.x * blockDim.x + threadIdx.x;
    const int w    = (int)(gtid >> 5);
    const int lane = threadIdx.x & 31;
    if (w >= NE) return;
    int beg = toff[w], end = toff[w + 1];
    if (beg < 0) beg = 0;
    if (end > NT) end = NT;

    const bf16x8 kv = *(const bf16x8*)(k + (size_t)w * HID + lane * 8);
    float kf[8];
#pragma unroll
    for (int j = 0; j < 8; ++j) kf[j] = bf2f((unsigned short)kv[j]);

    float av[8];
#pragma unroll
    for (int j = 0; j < 8; ++j) av[j] = 0.f;
    float den = 0.f;

    int kj_next = (beg < end) ? tkj[beg] : -1;
    for (int p = beg; p < end; ++p) {
        const int kj = kj_next;
        if (p + 1 < end) kj_next = tkj[p + 1];
        if ((unsigned)kj >= (unsigned)NE) continue;
        const bf16x8 qv = *(const bf16x8*)(q + (size_t)kj * HID + lane * 8);
        float s = 0.f;
#pragma unroll
        for (int j = 0; j < 8; ++j) s += bf2f((unsigned short)qv[j]) * kf[j];
        s += __shfl_xor(s, 1);
        s += __shfl_xor(s, 2);
        const float lr = (s > 0.f) ? s : 0.2f * s;
        const float a  = __expf(lr);
        den += a;
        const bf16x8 vv = *(const bf16x8*)(v + (size_t)kj * HID + lane * 8);
#pragma unroll
        for (int j = 0; j < 8; ++j) av[j] += a * bf2f((unsigned short)vv[j]);
    }
    const float inv = (den != 0.f) ? 1.f / den : 0.f;
    bf16x8 o;
#pragma unroll
    for (int j = 0; j < 8; ++j) o[j] = (short)f2bf(av[j] * inv);
    *(bf16x8*)(vc + (size_t)w * HID + lane * 8) = o;
}

// ---------------------------------------------------------------------------
// edge->node gather: 32 lanes per node, bf16x8 loads, writes bf16 DIRECTLY
// into finalA cols [0,256) (row stride 448). Saves the fsum f32 round-trip.
// ---------------------------------------------------------------------------
__global__ __launch_bounds__(256)
void gather_node(const unsigned short* __restrict__ feats,
                 const int* __restrict__ noff, const int* __restrict__ nlist,
                 unsigned short* __restrict__ outA)
{
    const long gtid = (long)blockIdx.x * blockDim.x + threadIdx.x;
    const int w    = (int)(gtid >> 5);
    const int lane = threadIdx.x & 31;
    if (w >= NN) return;
    int beg = noff[w], end = noff[w + 1];
    if (beg < 0) beg = 0;
    if (end > NT + NE) end = NT + NE;
    float av[8];
#pragma unroll
    for (int j = 0; j < 8; ++j) av[j] = 0.f;
    int e_next = (beg < end) ? nlist[beg] : -1;
    for (int p = beg; p < end; ++p) {
        const int e = e_next;
        if (p + 1 < end) e_next = nlist[p + 1];
        if ((unsigned)e >= (unsigned)NE) continue;
        const bf16x8 f = *(const bf16x8*)(feats + (size_t)e * HID + lane * 8);
#pragma unroll
        for (int j = 0; j < 8; ++j) av[j] += bf2f((unsigned short)f[j]);
    }
    bf16x8 o;
#pragma unroll
    for (int j = 0; j < 8; ++j) o[j] = (short)f2bf(av[j]);
    *(bf16x8*)(outA + (size_t)w * 448 + lane * 8) = o;
}

// ---------------------------------------------------------------------------
extern "C" void kernel_launch(void* const* d_in, const int* in_sizes, int n_in,
                              void* d_out, int out_size, void* d_ws, size_t ws_size,
                              hipStream_t stream)
{
    const float* atom = (const float*)d_in[0];
    const float* edge = (const float*)d_in[1];
    const float* W_i  = (const float*)d_in[2];
    const float* Wq   = (const float*)d_in[3];
    const float* Wk   = (const float*)d_in[4];
    const float* Wv   = (const float*)d_in[5];
    const float* L1w  = (const float*)d_in[6];
    const float* L1b  = (const float*)d_in[7];
    const float* L2w  = (const float*)d_in[8];
    const float* L2b  = (const float*)d_in[9];
    const float* Wo   = (const float*)d_in[10];
    const float* bo   = (const float*)d_in[11];
    const int* src    = (const int*)d_in[12];
    const int* dst    = (const int*)d_in[13];
    const int* idx_kj = (const int*)d_in[14];
    const int* idx_ji = (const int*)d_in[15];

    const size_t RB = (size_t)NE * HID * 2;   // 102,400,000 B
    char* ws = (char*)d_ws;
    unsigned short* feats = (unsigned short*)(ws);
    unsigned short* qb    = (unsigned short*)(ws + RB);
    unsigned short* kb    = (unsigned short*)(ws + 2 * RB);
    unsigned short* vb    = (unsigned short*)d_out;     // NE*256 bf16 == d_out bytes
    unsigned short* vc    = feats;                      // v_clone overlays feats
    unsigned short* initA = qb;                         // NEP*192 bf16 = 76.8MB < RB
    unsigned short* h1    = kb;
    unsigned short* finalA = kb;                        // NNP*448 bf16 = 89.7MB < RB

    const int NK = NE + NN;                 // combined key count
    char* p = ws + 3 * RB;
    int* offs     = (int*)p; p += ((size_t)NK + 16) * 4;
    int* cur      = (int*)p; p += ((size_t)NK + 16) * 4;
    int* plist    = (int*)p; p += (size_t)(NT + NE) * 4;
    int* tmp_excl = (int*)p; p += ((size_t)NK + 16) * 4;
    int* partials = (int*)p; p += 1024;
    unsigned short* wiT = (unsigned short*)p; p += (size_t)256 * 192 * 2;
    unsigned short* wT0 = (unsigned short*)p; p += (size_t)10 * 65536 * 2;
    unsigned short* woT = (unsigned short*)p; p += (size_t)256 * 448 * 2;
    const size_t NEEDED = (size_t)(p - ws);
    if (ws_size < NEEDED) return;
    auto wT = [&](int i) { return wT0 + (size_t)i * 65536; };

    const int MT_E  = NEP / 128;                 // 1563 M-tiles (edge GEMMs)
    const int MT_E8 = ((MT_E + 7) / 8) * 8;      // 1568
    const int MT_N  = NNP / 128;                 // 782 (final GEMM)
    const int MT_N8 = ((MT_N + 7) / 8) * 8;      // 784
    const int NPARTS = (NK + 2047) / 2048;       // 147 <= 256

    // ---- weight convert/transpose/pad (bf16) ----
    wconv<<<192, 256, 0, stream>>>(W_i, wiT, 147, 192);
    wconv10<<<dim3(256, 10), 256, 0, stream>>>(Wq, Wk, Wv, L1w, L2w, wT0);
    wconv_wo<<<448, 256, 0, stream>>>(Wo, woT);

    // ---- combined CSR build ----
    hipMemsetAsync(cur, 0, (size_t)NK * 4, stream);
    count_keys<<<(NT + 255) / 256, 256, 0, stream>>>(idx_ji, NT, NE, cur);
    count_keys<<<(NE + 255) / 256, 256, 0, stream>>>(dst, NE, NN, cur + NE);
    scan1<<<NPARTS, 256, 0, stream>>>(cur, NK, tmp_excl, partials);
    scan2<<<1, 256, 0, stream>>>(partials, NPARTS);
    scan3<<<(NK + 255) / 256, 256, 0, stream>>>(tmp_excl, partials, cur, NK, offs, cur);
    fill_trip<<<(NT + 255) / 256, 256, 0, stream>>>(idx_ji, idx_kj, cur, plist);
    fill_node<<<(NE + 255) / 256, 256, 0, stream>>>(dst, cur, plist);

    // ---- init: feats = relu(concat(atom[src], edge) @ W_i) ----
    {
        const long total = (long)NE * 192;
        build_initA<<<(int)((total + 255) / 256), 256, 0, stream>>>(atom, edge, src, initA);
    }
    gemm128<1, true><<<MT_E8 * 2, 256, 0, stream>>>(initA, wiT, nullptr, nullptr,
                                                    feats, MT_E, NE, 192);

    // ---- 2 attention layers ----
    for (int l = 0; l < 2; ++l) {
        const float* l1b = L1b + (size_t)l * 256;
        const float* l2b = L2b + (size_t)l * 256;

        gemm128_qkv<<<MT_E8 * 6, 256, 0, stream>>>(
            feats, wT(l * 5 + 0), wT(l * 5 + 1), wT(l * 5 + 2), qb, kb, vb, MT_E);

        gather_v<<<(NE * 32) / 256, 256, 0, stream>>>(qb, kb, vb, offs, plist, vc);

        // h1 = relu(vc @ L1 + b1); feats = v + relu(h1 @ L2 + b2)
        gemm128<3, true><<<MT_E8 * 2, 256, 0, stream>>>(vc, wT(l * 5 + 3), l1b,
                                                        nullptr, h1, MT_E, NE, 256);
        gemm128<7, true><<<MT_E8 * 2, 256, 0, stream>>>(h1, wT(l * 5 + 4), l2b,
                                                        vb, feats, MT_E, NE, 256);
    }

    // ---- final projection: finalA = [fsum | atom | 0] (permuted K) ----
    hipMemsetAsync(finalA + (size_t)NN * 448, 0,
                   (size_t)(NNP - NN) * 448 * 2, stream);          // pad rows
    gather_node<<<(NN * 32) / 256, 256, 0, stream>>>(feats, offs + NE, plist, finalA);
    {
        const long total = (long)NN * 192;
        build_final_atom<<<(int)((total + 255) / 256), 256, 0, stream>>>(atom, finalA);
    }
    gemm128<3, false><<<MT_N8 * 2, 256, 0, stream>>>(finalA, woT, bo, nullptr,
                                                     d_out, MT_N, NN, 448);
}

// Round 16
// 1149.044 us; speedup vs baseline: 1.8138x; 1.0509x over previous
//
#include <hip/hip_runtime.h>
#include <stdint.h>

#define NN 100000
#define NNP 100096          // NN padded to multiple of 128
#define NE 200000
#define NEP 200064          // NE padded to multiple of 128
#define NT 600000
#define HID 256

typedef __attribute__((ext_vector_type(8))) short bf16x8;
typedef __attribute__((ext_vector_type(4))) float f32x4;

__device__ __forceinline__ float bf2f(unsigned short u) {
    union { unsigned int i; float f; } x; x.i = ((unsigned int)u) << 16; return x.f;
}
__device__ __forceinline__ unsigned short f2bf(float f) {
    union { float f; unsigned int i; } x; x.f = f;
    unsigned int r = (x.i + 0x7FFFu + ((x.i >> 16) & 1u)) >> 16;
    return (unsigned short)r;
}

// async global->LDS, 16B per lane; LDS dest = wave-uniform base + lane*16
__device__ __forceinline__ void gload16(const void* g, void* l) {
    __builtin_amdgcn_global_load_lds(
        (const __attribute__((address_space(1))) void*)g,
        (__attribute__((address_space(3))) void*)l, 16, 0, 0);
}

// ---------------------------------------------------------------------------
// m97-style GEMM core (round-13 proven form — FROZEN):
// 4 waves (2x2), wave tile 64x64, BK=64, 32 KB LDS, 2-barrier loop,
// gload_lds staging, rule-21 swizzle pair.
// FAILED RESTRUCTURES (counter-evidenced): C^T epilogue swap (r12, -7%);
// multi-tile persistent loop (r14: acc spill, WRITE x3.3, MfmaUtil 3%);
// (256,5)/(512,6) bounds (r8/r10 spills); dbuf at 8 waves/CU (r5: 196 vs
// 151 us — TLP beats block-ILP here). Register budget: 512 wave-regs/SIMD
// unified VGPR+AGPR; 64 acc + ~60 addr = 124; (256,4) caps 128 — no slack.
// ---------------------------------------------------------------------------
template<int FLAGS, bool CBF>
__device__ __forceinline__
void gemm128_core(const unsigned short* __restrict__ A,
                  const unsigned short* __restrict__ BT,
                  const float* __restrict__ bias,
                  const unsigned short* __restrict__ res,
                  void* __restrict__ Cv, int row0, int col0,
                  int Mreal, int Kpad,
                  unsigned short* Asb, unsigned short* Bsb)
{
    const int t    = threadIdx.x;
    const int lane = t & 63;
    const int wv   = t >> 6;          // 0..3
    const int wr   = wv >> 1;         // wave row half
    const int wc   = wv & 1;          // wave col half
    const int l15  = lane & 15;
    const int lk   = lane >> 4;
    const int sub  = lane >> 3;       // staging sub-row 0..7
    const int schk = lane & 7;        // staging 16B chunk 0..7

    f32x4 acc[4][4];
#pragma unroll
    for (int i = 0; i < 4; ++i)
#pragma unroll
        for (int j = 0; j < 4; ++j) acc[i][j] = (f32x4){0.f, 0.f, 0.f, 0.f};

    const int nt = Kpad >> 6;
    for (int kt = 0; kt < nt; ++kt) {
        const int k0 = kt << 6;
#pragma unroll
        for (int j = 0; j < 4; ++j) {
            const int ii = wv * 4 + j;
            const int r  = ii * 8 + sub;
            const int cg = schk ^ (r & 7);
            gload16(A + (size_t)(row0 + r) * Kpad + k0 + cg * 8, Asb + ii * 512);
        }
#pragma unroll
        for (int j = 0; j < 4; ++j) {
            const int ii = wv * 4 + j;
            const int r  = ii * 8 + sub;
            const int cg = schk ^ (r & 7);
            gload16(BT + (size_t)(col0 + r) * Kpad + k0 + cg * 8, Bsb + ii * 512);
        }
        __syncthreads();     // compiler drains vmcnt before s_barrier
#pragma unroll
        for (int ks = 0; ks < 2; ++ks) {
            bf16x8 af[4], bfg[4];
#pragma unroll
            for (int mi = 0; mi < 4; ++mi) {
                const int r = wr * 64 + mi * 16 + l15;
                const int c = ks * 4 + lk;
                af[mi] = *(const bf16x8*)((const char*)Asb
                          + r * 128 + ((c ^ (r & 7)) << 4));
            }
#pragma unroll
            for (int ni = 0; ni < 4; ++ni) {
                const int r = wc * 64 + ni * 16 + l15;
                const int c = ks * 4 + lk;
                bfg[ni] = *(const bf16x8*)((const char*)Bsb
                           + r * 128 + ((c ^ (r & 7)) << 4));
            }
#pragma unroll
            for (int mi = 0; mi < 4; ++mi)
#pragma unroll
                for (int ni = 0; ni < 4; ++ni)
                    acc[mi][ni] = __builtin_amdgcn_mfma_f32_16x16x32_bf16(
                        af[mi], bfg[ni], acc[mi][ni], 0, 0, 0);
        }
        __syncthreads();     // reads done before next stage overwrites
    }

    // epilogue: D col=l&15, row=(l>>4)*4+reg  [m89-verified]
#pragma unroll
    for (int mi = 0; mi < 4; ++mi) {
#pragma unroll
        for (int r = 0; r < 4; ++r) {
            const int row = row0 + wr * 64 + mi * 16 + lk * 4 + r;
            if (row >= Mreal) continue;
#pragma unroll
            for (int ni = 0; ni < 4; ++ni) {
                const int col = col0 + wc * 64 + ni * 16 + l15;
                float o = acc[mi][ni][r];
                if (FLAGS & 2) o += bias[col];
                if (FLAGS & 1) o = fmaxf(o, 0.f);
                if (FLAGS & 4) o += bf2f(res[(size_t)row * HID + col]);
                if (CBF) ((unsigned short*)Cv)[(size_t)row * HID + col] = f2bf(o);
                else     ((float*)Cv)[(size_t)row * HID + col] = o;
            }
        }
    }
}

// XCD-aware swizzle [T1]: x = xcd + 8*(member + MEMBERS*local_group).
template<int FLAGS, bool CBF>
__global__ __launch_bounds__(256, 4)
void gemm128(const unsigned short* __restrict__ A,
             const unsigned short* __restrict__ BT,
             const float* __restrict__ bias,
             const unsigned short* __restrict__ res,
             void* __restrict__ Cv, int Mtiles, int Mreal, int Kpad)
{
    __shared__ alignas(16) unsigned short Asb[128 * 64];
    __shared__ alignas(16) unsigned short Bsb[128 * 64];
    const int x   = blockIdx.x;
    const int xcd = x & 7;
    const int ii  = x >> 3;
    const int g   = (ii >> 1) * 8 + xcd;     // tile-group = M tile
    const int ch  = ii & 1;
    if (g >= Mtiles) return;
    gemm128_core<FLAGS, CBF>(A, BT, bias, res, Cv, g * 128, ch * 128,
                             Mreal, Kpad, Asb, Bsb);
}

// qkv: grid.x = Mtiles8 * 6; 6 members (3 proj x 2 halves) share one A tile
__global__ __launch_bounds__(256, 4)
void gemm128_qkv(const unsigned short* __restrict__ A,
                 const unsigned short* __restrict__ BTq,
                 const unsigned short* __restrict__ BTk,
                 const unsigned short* __restrict__ BTv,
                 unsigned short* __restrict__ Cq,
                 unsigned short* __restrict__ Ck,
                 unsigned short* __restrict__ Cvp, int Mtiles)
{
    __shared__ alignas(16) unsigned short Asb[128 * 64];
    __shared__ alignas(16) unsigned short Bsb[128 * 64];
    const int x   = blockIdx.x;
    const int xcd = x & 7;
    const int ii  = x >> 3;
    const int g   = (ii / 6) * 8 + xcd;
    const int j   = ii % 6;
    if (g >= Mtiles) return;
    const int proj = j >> 1;
    const int ch   = j & 1;
    const unsigned short* BT = (proj == 0) ? BTq : (proj == 1) ? BTk : BTv;
    unsigned short*       C  = (proj == 0) ? Cq  : (proj == 1) ? Ck  : Cvp;
    gemm128_core<0, true>(A, BT, nullptr, nullptr, C, g * 128, ch * 128,
                          NE, 256, Asb, Bsb);
}

// ---------------------------------------------------------------------------
__global__ __launch_bounds__(256)
void wconv(const float* __restrict__ W, unsigned short* __restrict__ BT,
           int Kreal, int Kpad)
{
    const int idx = blockIdx.x * 256 + threadIdx.x;
    const int n = idx / Kpad, kp = idx - n * Kpad;
    float v = (kp < Kreal) ? W[(size_t)kp * HID + n] : 0.f;
    BT[idx] = f2bf(v);
}

// Wo with PERMUTED K: kp<256 -> Wo row 133+kp (fsum part); 256<=kp<389 ->
// Wo row kp-256 (atom part); else 0. Must match finalA column layout.
__global__ __launch_bounds__(256)
void wconv_wo(const float* __restrict__ W, unsigned short* __restrict__ BT)
{
    const int idx = blockIdx.x * 256 + threadIdx.x;   // grid 448 blocks
    const int n = idx / 448, kp = idx - n * 448;
    float v = 0.f;
    if (kp < 256)      v = W[(size_t)(133 + kp) * HID + n];
    else if (kp < 389) v = W[(size_t)(kp - 256) * HID + n];
    BT[idx] = f2bf(v);
}

__global__ __launch_bounds__(256)
void wconv10(const float* __restrict__ Wq, const float* __restrict__ Wk,
             const float* __restrict__ Wv, const float* __restrict__ L1w,
             const float* __restrict__ L2w, unsigned short* __restrict__ outbase)
{
    const int y = blockIdx.y;
    const int l = y / 5, which = y - l * 5;
    const float* src;
    switch (which) {
        case 0: src = Wq;  break;
        case 1: src = Wk;  break;
        case 2: src = Wv;  break;
        case 3: src = L1w; break;
        default: src = L2w; break;
    }
    src += (size_t)l * 65536;
    const int idx = blockIdx.x * 256 + threadIdx.x;
    const int n = idx >> 8, kp = idx & 255;
    outbase[(size_t)y * 65536 + idx] = f2bf(src[(size_t)kp * HID + n]);
}

// ---------------------------------------------------------------------------
// initA build, vectorized: thread per 8-col chunk (24 chunks/row of 192)
// ---------------------------------------------------------------------------
__global__ __launch_bounds__(256)
void build_initA(const float* __restrict__ atom, const float* __restrict__ edge,
                 const int* __restrict__ src, unsigned short* __restrict__ out)
{
    const int idx = blockIdx.x * 256 + threadIdx.x;
    const int e = idx / 24, j = idx - e * 24;
    if (e >= NE) return;
    const int c0 = j * 8;
    const int s  = src[e];
    bf16x8 o;
#pragma unroll
    for (int i = 0; i < 8; ++i) {
        const int c = c0 + i;
        float v = 0.f;
        if (c < 133)      v = atom[(size_t)s * 133 + c];
        else if (c < 147) v = edge[(size_t)e * 14 + (c - 133)];
        o[i] = (short)f2bf(v);
    }
    *(bf16x8*)(out + (size_t)e * 192 + c0) = o;
}

// fill finalA atom columns [256,389) + zero pad [389,448), rows < NN.
// thread per 8-col chunk (24 chunks covering cols 256..447).
__global__ __launch_bounds__(256)
void build_final_atom(const float* __restrict__ atom, unsigned short* __restrict__ out)
{
    const int idx = blockIdx.x * 256 + threadIdx.x;
    const int n = idx / 24, j = idx - n * 24;
    if (n >= NN) return;
    const int c0 = j * 8;
    bf16x8 o;
#pragma unroll
    for (int i = 0; i < 8; ++i) {
        const int c = c0 + i;
        float v = (c < 133) ? atom[(size_t)n * 133 + c] : 0.f;
        o[i] = (short)f2bf(v);
    }
    *(bf16x8*)(out + (size_t)n * 448 + 256 + c0) = o;
}

// ---------------------------------------------------------------------------
// Combined CSR build: counts/offsets over triplet keys [0,NE) + node keys
// [NE, NE+NN); one scan chain. plist: [0,NT) kj per triplet slot;
// [NT,NT+NE) edge id per node slot.
// ---------------------------------------------------------------------------
__global__ __launch_bounds__(256)
void count_keys(const int* __restrict__ key, int n, int nkeys, int* __restrict__ cnt)
{
    const int i = blockIdx.x * 256 + threadIdx.x;
    if (i < n) {
        const int kk = key[i];
        if ((unsigned)kk < (unsigned)nkeys) atomicAdd(&cnt[kk], 1);
    }
}

__global__ __launch_bounds__(256)
void fill_trip(const int* __restrict__ idx_ji, const int* __restrict__ idx_kj,
               int* __restrict__ cur, int* __restrict__ plist)
{
    const int i = blockIdx.x * 256 + threadIdx.x;
    if (i >= NT) return;
    const int kk = idx_ji[i];
    if ((unsigned)kk >= (unsigned)NE) return;
    const int pos = atomicAdd(&cur[kk], 1);
    if ((unsigned)pos < (unsigned)NT) plist[pos] = idx_kj[i];
}

__global__ __launch_bounds__(256)
void fill_node(const int* __restrict__ dst, int* __restrict__ cur,
               int* __restrict__ plist)
{
    const int i = blockIdx.x * 256 + threadIdx.x;
    if (i >= NE) return;
    const int kk = dst[i];
    if ((unsigned)kk >= (unsigned)NN) return;
    const int pos = atomicAdd(&cur[NE + kk], 1);
    if ((unsigned)pos < (unsigned)(NT + NE)) plist[pos] = i;
}

// per-block (2048 elems, 8/thread) exclusive scan; partials out (<=256 blocks)
__global__ __launch_bounds__(256)
void scan1(const int* __restrict__ in, int n, int* __restrict__ excl,
           int* __restrict__ part)
{
    __shared__ int sh[256];
    const int t = threadIdx.x;
    const int base = blockIdx.x * 2048 + t * 8;
    int v[8]; int s = 0;
#pragma unroll
    for (int j = 0; j < 8; ++j) { v[j] = (base + j < n) ? in[base + j] : 0; s += v[j]; }
    sh[t] = s; __syncthreads();
    for (int off = 1; off < 256; off <<= 1) {
        int x = (t >= off) ? sh[t - off] : 0;
        __syncthreads();
        sh[t] += x;
        __syncthreads();
    }
    int ex = sh[t] - s;
#pragma unroll
    for (int j = 0; j < 8; ++j) { if (base + j < n) excl[base + j] = ex; ex += v[j]; }
    if (t == 255) part[blockIdx.x] = sh[255];
}

__global__ __launch_bounds__(256)
void scan2(int* __restrict__ part, int nparts)
{
    __shared__ int sh[256];
    const int t = threadIdx.x;
    const int v = (t < nparts) ? part[t] : 0;
    sh[t] = v; __syncthreads();
    for (int off = 1; off < 256; off <<= 1) {
        int x = (t >= off) ? sh[t - off] : 0;
        __syncthreads();
        sh[t] += x;
        __syncthreads();
    }
    if (t < nparts) part[t] = sh[t] - v;
}

__global__ __launch_bounds__(256)
void scan3(const int* __restrict__ excl, const int* __restrict__ part,
           const int* counts, int n, int* __restrict__ offs, int* cur)
{
    const int i = blockIdx.x * 256 + threadIdx.x;
    if (i >= n) return;
    const int v = excl[i] + part[i >> 11];
    const int c = counts[i];
    offs[i] = v;
    cur[i] = v;
    if (i == n - 1) offs[n] = v + c;
}

// ---------------------------------------------------------------------------
// Fused attention gather: 16 lanes per edge (4 edges/wave) + 1-deep q/v
// value prefetch. Lane covers 16 dims (32 B); head reduce = 1 shfl_xor.
// ---------------------------------------------------------------------------
__global__ __launch_bounds__(256)
void gather_v(const unsigned short* __restrict__ q, const unsigned short* __restrict__ k,
              const unsigned short* __restrict__ v,
              const int* __restrict__ toff, const int* __restrict__ tkj,
              unsigned short* __restrict__ vc)
{
    const long gtid = (long)blockIdx.x * blockDim.x + threadIdx.x;
    const int w    = (int)(gtid >> 4);          // edge id
    const int lane = threadIdx.x & 15;          // 16 dims per lane
    if (w >= NE) return;
    int beg = toff[w], end = toff[w + 1];
    if (beg < 0) beg = 0;
    if (end > NT) end = NT;

    const size_t lo = (size_t)w * HID + lane * 16;
    const bf16x8 k0 = *(const bf16x8*)(k + lo);
    const bf16x8 k1 = *(const bf16x8*)(k + lo + 8);
    float kf[16];
#pragma unroll
    for (int j = 0; j < 8; ++j) { kf[j] = bf2f((unsigned short)k0[j]);
                                  kf[j + 8] = bf2f((unsigned short)k1[j]); }
    float av[16];
#pragma unroll
    for (int j = 0; j < 16; ++j) av[j] = 0.f;
    float den = 0.f;

    // prefetch slot
    bool okn = false; int an = 0;
    if (beg < end) {
        const int t0 = tkj[beg];
        okn = (unsigned)t0 < (unsigned)NE;
        an = okn ? t0 : 0;
    }
    bf16x8 qn0 = *(const bf16x8*)(q + (size_t)an * HID + lane * 16);
    bf16x8 qn1 = *(const bf16x8*)(q + (size_t)an * HID + lane * 16 + 8);
    bf16x8 vn0 = *(const bf16x8*)(v + (size_t)an * HID + lane * 16);
    bf16x8 vn1 = *(const bf16x8*)(v + (size_t)an * HID + lane * 16 + 8);

    for (int p = beg; p < end; ++p) {
        const bf16x8 q0 = qn0, q1 = qn1, v0 = vn0, v1 = vn1;
        const bool ok = okn;
        if (p + 1 < end) {
            const int tn = tkj[p + 1];
            okn = (unsigned)tn < (unsigned)NE;
            const int a2 = okn ? tn : 0;
            qn0 = *(const bf16x8*)(q + (size_t)a2 * HID + lane * 16);
            qn1 = *(const bf16x8*)(q + (size_t)a2 * HID + lane * 16 + 8);
            vn0 = *(const bf16x8*)(v + (size_t)a2 * HID + lane * 16);
            vn1 = *(const bf16x8*)(v + (size_t)a2 * HID + lane * 16 + 8);
        }
        if (!ok) continue;
        float s = 0.f;
#pragma unroll
        for (int j = 0; j < 8; ++j) {
            s += bf2f((unsigned short)q0[j]) * kf[j];
            s += bf2f((unsigned short)q1[j]) * kf[j + 8];
        }
        s += __shfl_xor(s, 1);                  // head = 2 lanes (d=32)
        const float lr = (s > 0.f) ? s : 0.2f * s;
        const float a  = __expf(lr);
        den += a;
#pragma unroll
        for (int j = 0; j < 8; ++j) {
            av[j]     += a * bf2f((unsigned short)v0[j]);
            av[j + 8] += a * bf2f((unsigned short)v1[j]);
        }
    }
    const float inv = (den != 0.f) ? 1.f / den : 0.f;
    bf16x8 o0, o1;
#pragma unroll
    for (int j = 0; j < 8; ++j) {
        o0[j] = (short)f2bf(av[j] * inv);
        o1[j] = (short)f2bf(av[j + 8] * inv);
    }
    *(bf16x8*)(vc + lo)     = o0;
    *(bf16x8*)(vc + lo + 8) = o1;
}

// ---------------------------------------------------------------------------
// edge->node gather: 16 lanes per node + value prefetch; writes bf16 directly
// into finalA cols [0,256) (row stride 448).
// ---------------------------------------------------------------------------
__global__ __launch_bounds__(256)
void gather_node(const unsigned short* __restrict__ feats,
                 const int* __restrict__ noff, const int* __restrict__ nlist,
                 unsigned short* __restrict__ outA)
{
    const long gtid = (long)blockIdx.x * blockDim.x + threadIdx.x;
    const int w    = (int)(gtid >> 4);
    const int lane = threadIdx.x & 15;
    if (w >= NN) return;
    int beg = noff[w], end = noff[w + 1];
    if (beg < 0) beg = 0;
    if (end > NT + NE) end = NT + NE;

    float av[16];
#pragma unroll
    for (int j = 0; j < 16; ++j) av[j] = 0.f;

    bool okn = false; int an = 0;
    if (beg < end) {
        const int e0 = nlist[beg];
        okn = (unsigned)e0 < (unsigned)NE;
        an = okn ? e0 : 0;
    }
    bf16x8 fn0 = *(const bf16x8*)(feats + (size_t)an * HID + lane * 16);
    bf16x8 fn1 = *(const bf16x8*)(feats + (size_t)an * HID + lane * 16 + 8);

    for (int p = beg; p < end; ++p) {
        const bf16x8 f0 = fn0, f1 = fn1;
        const bool ok = okn;
        if (p + 1 < end) {
            const int en = nlist[p + 1];
            okn = (unsigned)en < (unsigned)NE;
            const int a2 = okn ? en : 0;
            fn0 = *(const bf16x8*)(feats + (size_t)a2 * HID + lane * 16);
            fn1 = *(const bf16x8*)(feats + (size_t)a2 * HID + lane * 16 + 8);
        }
        if (!ok) continue;
#pragma unroll
        for (int j = 0; j < 8; ++j) {
            av[j]     += bf2f((unsigned short)f0[j]);
            av[j + 8] += bf2f((unsigned short)f1[j]);
        }
    }
    bf16x8 o0, o1;
#pragma unroll
    for (int j = 0; j < 8; ++j) {
        o0[j] = (short)f2bf(av[j]);
        o1[j] = (short)f2bf(av[j + 8]);
    }
    unsigned short* out = outA + (size_t)w * 448 + lane * 16;
    *(bf16x8*)(out)     = o0;
    *(bf16x8*)(out + 8) = o1;
}

// ---------------------------------------------------------------------------
extern "C" void kernel_launch(void* const* d_in, const int* in_sizes, int n_in,
                              void* d_out, int out_size, void* d_ws, size_t ws_size,
                              hipStream_t stream)
{
    const float* atom = (const float*)d_in[0];
    const float* edge = (const float*)d_in[1];
    const float* W_i  = (const float*)d_in[2];
    const float* Wq   = (const float*)d_in[3];
    const float* Wk   = (const float*)d_in[4];
    const float* Wv   = (const float*)d_in[5];
    const float* L1w  = (const float*)d_in[6];
    const float* L1b  = (const float*)d_in[7];
    const float* L2w  = (const float*)d_in[8];
    const float* L2b  = (const float*)d_in[9];
    const float* Wo   = (const float*)d_in[10];
    const float* bo   = (const float*)d_in[11];
    const int* src    = (const int*)d_in[12];
    const int* dst    = (const int*)d_in[13];
    const int* idx_kj = (const int*)d_in[14];
    const int* idx_ji = (const int*)d_in[15];

    const size_t RB = (size_t)NE * HID * 2;   // 102,400,000 B
    char* ws = (char*)d_ws;
    unsigned short* feats = (unsigned short*)(ws);
    unsigned short* qb    = (unsigned short*)(ws + RB);
    unsigned short* kb    = (unsigned short*)(ws + 2 * RB);
    unsigned short* vb    = (unsigned short*)d_out;     // NE*256 bf16 == d_out bytes
    unsigned short* vc    = feats;                      // v_clone overlays feats
    unsigned short* initA = qb;                         // NEP*192 bf16 = 76.8MB < RB
    unsigned short* h1    = kb;
    unsigned short* finalA = kb;                        // NNP*448 bf16 = 89.7MB < RB

    const int NK = NE + NN;                 // combined key count
    char* p = ws + 3 * RB;
    int* offs     = (int*)p; p += ((size_t)NK + 16) * 4;
    int* cur      = (int*)p; p += ((size_t)NK + 16) * 4;
    int* plist    = (int*)p; p += (size_t)(NT + NE) * 4;
    int* tmp_excl = (int*)p; p += ((size_t)NK + 16) * 4;
    int* partials = (int*)p; p += 1024;
    unsigned short* wiT = (unsigned short*)p; p += (size_t)256 * 192 * 2;
    unsigned short* wT0 = (unsigned short*)p; p += (size_t)10 * 65536 * 2;
    unsigned short* woT = (unsigned short*)p; p += (size_t)256 * 448 * 2;
    const size_t NEEDED = (size_t)(p - ws);
    if (ws_size < NEEDED) return;
    auto wT = [&](int i) { return wT0 + (size_t)i * 65536; };

    const int MT_E  = NEP / 128;                 // 1563 M-tiles (edge GEMMs)
    const int MT_E8 = ((MT_E + 7) / 8) * 8;      // 1568
    const int MT_N  = NNP / 128;                 // 782 (final GEMM)
    const int MT_N8 = ((MT_N + 7) / 8) * 8;      // 784
    const int NPARTS = (NK + 2047) / 2048;       // 147 <= 256

    // ---- weight convert/transpose/pad (bf16) ----
    wconv<<<192, 256, 0, stream>>>(W_i, wiT, 147, 192);
    wconv10<<<dim3(256, 10), 256, 0, stream>>>(Wq, Wk, Wv, L1w, L2w, wT0);
    wconv_wo<<<448, 256, 0, stream>>>(Wo, woT);

    // ---- combined CSR build ----
    hipMemsetAsync(cur, 0, (size_t)NK * 4, stream);
    count_keys<<<(NT + 255) / 256, 256, 0, stream>>>(idx_ji, NT, NE, cur);
    count_keys<<<(NE + 255) / 256, 256, 0, stream>>>(dst, NE, NN, cur + NE);
    scan1<<<NPARTS, 256, 0, stream>>>(cur, NK, tmp_excl, partials);
    scan2<<<1, 256, 0, stream>>>(partials, NPARTS);
    scan3<<<(NK + 255) / 256, 256, 0, stream>>>(tmp_excl, partials, cur, NK, offs, cur);
    fill_trip<<<(NT + 255) / 256, 256, 0, stream>>>(idx_ji, idx_kj, cur, plist);
    fill_node<<<(NE + 255) / 256, 256, 0, stream>>>(dst, cur, plist);

    // ---- init: feats = relu(concat(atom[src], edge) @ W_i) ----
    build_initA<<<(NE * 24 + 255) / 256, 256, 0, stream>>>(atom, edge, src, initA);
    gemm128<1, true><<<MT_E8 * 2, 256, 0, stream>>>(initA, wiT, nullptr, nullptr,
                                                    feats, MT_E, NE, 192);

    // ---- 2 attention layers ----
    for (int l = 0; l < 2; ++l) {
        const float* l1b = L1b + (size_t)l * 256;
        const float* l2b = L2b + (size_t)l * 256;

        gemm128_qkv<<<MT_E8 * 6, 256, 0, stream>>>(
            feats, wT(l * 5 + 0), wT(l * 5 + 1), wT(l * 5 + 2), qb, kb, vb, MT_E);

        gather_v<<<(NE * 16) / 256, 256, 0, stream>>>(qb, kb, vb, offs, plist, vc);

        // h1 = relu(vc @ L1 + b1); feats = v + relu(h1 @ L2 + b2)
        gemm128<3, true><<<MT_E8 * 2, 256, 0, stream>>>(vc, wT(l * 5 + 3), l1b,
                                                        nullptr, h1, MT_E, NE, 256);
        gemm128<7, true><<<MT_E8 * 2, 256, 0, stream>>>(h1, wT(l * 5 + 4), l2b,
                                                        vb, feats, MT_E, NE, 256);
    }

    // ---- final projection: finalA = [fsum | atom | 0] (permuted K) ----
    hipMemsetAsync(finalA + (size_t)NN * 448, 0,
                   (size_t)(NNP - NN) * 448 * 2, stream);          // pad rows
    gather_node<<<(NN * 16) / 256, 256, 0, stream>>>(feats, offs + NE, plist, finalA);
    build_final_atom<<<(NN * 24 + 255) / 256, 256, 0, stream>>>(atom, finalA);
    gemm128<3, false><<<MT_N8 * 2, 256, 0, stream>>>(finalA, woT, bo, nullptr,
                                                     d_out, MT_N, NN, 448);
}

// Round 17
// 1139.458 us; speedup vs baseline: 1.8291x; 1.0084x over previous
//
#include <hip/hip_runtime.h>
#include <stdint.h>

#define NN 100000
#define NNP 100096          // NN padded to multiple of 128
#define NE 200000
#define NEP 200064          // NE padded to multiple of 128
#define NT 600000
#define HID 256

typedef __attribute__((ext_vector_type(8))) short bf16x8;
typedef __attribute__((ext_vector_type(4))) float f32x4;

__device__ __forceinline__ float bf2f(unsigned short u) {
    union { unsigned int i; float f; } x; x.i = ((unsigned int)u) << 16; return x.f;
}
__device__ __forceinline__ unsigned short f2bf(float f) {
    union { float f; unsigned int i; } x; x.f = f;
    unsigned int r = (x.i + 0x7FFFu + ((x.i >> 16) & 1u)) >> 16;
    return (unsigned short)r;
}

// async global->LDS, 16B per lane; LDS dest = wave-uniform base + lane*16
__device__ __forceinline__ void gload16(const void* g, void* l) {
    __builtin_amdgcn_global_load_lds(
        (const __attribute__((address_space(1))) void*)g,
        (__attribute__((address_space(3))) void*)l, 16, 0, 0);
}

// ---------------------------------------------------------------------------
// m97-style GEMM core (round-13 proven form — FROZEN):
// 4 waves (2x2), wave tile 64x64, BK=64, 32 KB LDS, 2-barrier loop,
// gload_lds staging, rule-21 swizzle pair.
// FAILED RESTRUCTURES (counter-evidenced): C^T epilogue swap (r12, -7%);
// multi-tile persistent loop (r14: acc spill, WRITE x3.3, MfmaUtil 3%);
// (256,5)/(512,6) bounds (r8/r10 spills); dbuf at 8 waves/CU (r5: 196 vs
// 151 us — TLP beats block-ILP here). Register budget: 512 wave-regs/SIMD
// unified VGPR+AGPR; 64 acc + ~60 addr = 124; (256,4) caps 128 — no slack.
// ---------------------------------------------------------------------------
template<int FLAGS, bool CBF>
__device__ __forceinline__
void gemm128_core(const unsigned short* __restrict__ A,
                  const unsigned short* __restrict__ BT,
                  const float* __restrict__ bias,
                  const unsigned short* __restrict__ res,
                  void* __restrict__ Cv, int row0, int col0,
                  int Mreal, int Kpad,
                  unsigned short* Asb, unsigned short* Bsb)
{
    const int t    = threadIdx.x;
    const int lane = t & 63;
    const int wv   = t >> 6;          // 0..3
    const int wr   = wv >> 1;         // wave row half
    const int wc   = wv & 1;          // wave col half
    const int l15  = lane & 15;
    const int lk   = lane >> 4;
    const int sub  = lane >> 3;       // staging sub-row 0..7
    const int schk = lane & 7;        // staging 16B chunk 0..7

    f32x4 acc[4][4];
#pragma unroll
    for (int i = 0; i < 4; ++i)
#pragma unroll
        for (int j = 0; j < 4; ++j) acc[i][j] = (f32x4){0.f, 0.f, 0.f, 0.f};

    const int nt = Kpad >> 6;
    for (int kt = 0; kt < nt; ++kt) {
        const int k0 = kt << 6;
#pragma unroll
        for (int j = 0; j < 4; ++j) {
            const int ii = wv * 4 + j;
            const int r  = ii * 8 + sub;
            const int cg = schk ^ (r & 7);
            gload16(A + (size_t)(row0 + r) * Kpad + k0 + cg * 8, Asb + ii * 512);
        }
#pragma unroll
        for (int j = 0; j < 4; ++j) {
            const int ii = wv * 4 + j;
            const int r  = ii * 8 + sub;
            const int cg = schk ^ (r & 7);
            gload16(BT + (size_t)(col0 + r) * Kpad + k0 + cg * 8, Bsb + ii * 512);
        }
        __syncthreads();     // compiler drains vmcnt before s_barrier
#pragma unroll
        for (int ks = 0; ks < 2; ++ks) {
            bf16x8 af[4], bfg[4];
#pragma unroll
            for (int mi = 0; mi < 4; ++mi) {
                const int r = wr * 64 + mi * 16 + l15;
                const int c = ks * 4 + lk;
                af[mi] = *(const bf16x8*)((const char*)Asb
                          + r * 128 + ((c ^ (r & 7)) << 4));
            }
#pragma unroll
            for (int ni = 0; ni < 4; ++ni) {
                const int r = wc * 64 + ni * 16 + l15;
                const int c = ks * 4 + lk;
                bfg[ni] = *(const bf16x8*)((const char*)Bsb
                           + r * 128 + ((c ^ (r & 7)) << 4));
            }
#pragma unroll
            for (int mi = 0; mi < 4; ++mi)
#pragma unroll
                for (int ni = 0; ni < 4; ++ni)
                    acc[mi][ni] = __builtin_amdgcn_mfma_f32_16x16x32_bf16(
                        af[mi], bfg[ni], acc[mi][ni], 0, 0, 0);
        }
        __syncthreads();     // reads done before next stage overwrites
    }

    // epilogue: D col=l&15, row=(l>>4)*4+reg  [m89-verified]
#pragma unroll
    for (int mi = 0; mi < 4; ++mi) {
#pragma unroll
        for (int r = 0; r < 4; ++r) {
            const int row = row0 + wr * 64 + mi * 16 + lk * 4 + r;
            if (row >= Mreal) continue;
#pragma unroll
            for (int ni = 0; ni < 4; ++ni) {
                const int col = col0 + wc * 64 + ni * 16 + l15;
                float o = acc[mi][ni][r];
                if (FLAGS & 2) o += bias[col];
                if (FLAGS & 1) o = fmaxf(o, 0.f);
                if (FLAGS & 4) o += bf2f(res[(size_t)row * HID + col]);
                if (CBF) ((unsigned short*)Cv)[(size_t)row * HID + col] = f2bf(o);
                else     ((float*)Cv)[(size_t)row * HID + col] = o;
            }
        }
    }
}

// XCD-aware swizzle [T1]: x = xcd + 8*(member + MEMBERS*local_group).
template<int FLAGS, bool CBF>
__global__ __launch_bounds__(256, 4)
void gemm128(const unsigned short* __restrict__ A,
             const unsigned short* __restrict__ BT,
             const float* __restrict__ bias,
             const unsigned short* __restrict__ res,
             void* __restrict__ Cv, int Mtiles, int Mreal, int Kpad)
{
    __shared__ alignas(16) unsigned short Asb[128 * 64];
    __shared__ alignas(16) unsigned short Bsb[128 * 64];
    const int x   = blockIdx.x;
    const int xcd = x & 7;
    const int ii  = x >> 3;
    const int g   = (ii >> 1) * 8 + xcd;     // tile-group = M tile
    const int ch  = ii & 1;
    if (g >= Mtiles) return;
    gemm128_core<FLAGS, CBF>(A, BT, bias, res, Cv, g * 128, ch * 128,
                             Mreal, Kpad, Asb, Bsb);
}

// qkv: grid.x = Mtiles8 * 6; 6 members (3 proj x 2 halves) share one A tile
__global__ __launch_bounds__(256, 4)
void gemm128_qkv(const unsigned short* __restrict__ A,
                 const unsigned short* __restrict__ BTq,
                 const unsigned short* __restrict__ BTk,
                 const unsigned short* __restrict__ BTv,
                 unsigned short* __restrict__ Cq,
                 unsigned short* __restrict__ Ck,
                 unsigned short* __restrict__ Cvp, int Mtiles)
{
    __shared__ alignas(16) unsigned short Asb[128 * 64];
    __shared__ alignas(16) unsigned short Bsb[128 * 64];
    const int x   = blockIdx.x;
    const int xcd = x & 7;
    const int ii  = x >> 3;
    const int g   = (ii / 6) * 8 + xcd;
    const int j   = ii % 6;
    if (g >= Mtiles) return;
    const int proj = j >> 1;
    const int ch   = j & 1;
    const unsigned short* BT = (proj == 0) ? BTq : (proj == 1) ? BTk : BTv;
    unsigned short*       C  = (proj == 0) ? Cq  : (proj == 1) ? Ck  : Cvp;
    gemm128_core<0, true>(A, BT, nullptr, nullptr, C, g * 128, ch * 128,
                          NE, 256, Asb, Bsb);
}

// ---------------------------------------------------------------------------
// All 12 weight conversions in ONE launch. grid = (448, 12).
//   y 0..9 : 256x256 square weights -> wT0 + y*65536 (l = y/5, which = y%5)
//   y = 10 : W_i  K=147 -> wiT padded 192
//   y = 11 : Wo   K-permuted (fsum rows first) -> woT padded 448
// ---------------------------------------------------------------------------
__global__ __launch_bounds__(256)
void wconv_all(const float* __restrict__ Wq, const float* __restrict__ Wk,
               const float* __restrict__ Wv, const float* __restrict__ L1w,
               const float* __restrict__ L2w, const float* __restrict__ W_i,
               const float* __restrict__ Wo,
               unsigned short* __restrict__ wT0,
               unsigned short* __restrict__ wiT,
               unsigned short* __restrict__ woT)
{
    const int y   = blockIdx.y;
    const int idx = blockIdx.x * 256 + threadIdx.x;
    if (y < 10) {
        if (idx >= 65536) return;
        const int l = y / 5, which = y - l * 5;
        const float* src;
        switch (which) {
            case 0: src = Wq;  break;
            case 1: src = Wk;  break;
            case 2: src = Wv;  break;
            case 3: src = L1w; break;
            default: src = L2w; break;
        }
        src += (size_t)l * 65536;
        const int n = idx >> 8, kp = idx & 255;
        wT0[(size_t)y * 65536 + idx] = f2bf(src[(size_t)kp * HID + n]);
    } else if (y == 10) {
        if (idx >= 256 * 192) return;
        const int n = idx / 192, kp = idx - n * 192;
        const float v = (kp < 147) ? W_i[(size_t)kp * HID + n] : 0.f;
        wiT[idx] = f2bf(v);
    } else {
        if (idx >= 256 * 448) return;
        const int n = idx / 448, kp = idx - n * 448;
        float v = 0.f;
        if (kp < 256)      v = Wo[(size_t)(133 + kp) * HID + n];
        else if (kp < 389) v = Wo[(size_t)(kp - 256) * HID + n];
        woT[idx] = f2bf(v);
    }
}

// ---------------------------------------------------------------------------
// initA build, vectorized: thread per 8-col chunk (24 chunks/row of 192)
// ---------------------------------------------------------------------------
__global__ __launch_bounds__(256)
void build_initA(const float* __restrict__ atom, const float* __restrict__ edge,
                 const int* __restrict__ src, unsigned short* __restrict__ out)
{
    const int idx = blockIdx.x * 256 + threadIdx.x;
    const int e = idx / 24, j = idx - e * 24;
    if (e >= NE) return;
    const int c0 = j * 8;
    const int s  = src[e];
    bf16x8 o;
#pragma unroll
    for (int i = 0; i < 8; ++i) {
        const int c = c0 + i;
        float v = 0.f;
        if (c < 133)      v = atom[(size_t)s * 133 + c];
        else if (c < 147) v = edge[(size_t)e * 14 + (c - 133)];
        o[i] = (short)f2bf(v);
    }
    *(bf16x8*)(out + (size_t)e * 192 + c0) = o;
}

// fill finalA atom columns [256,389) + zero pad [389,448) for ALL NNP rows
// (rows >= NN get zeros — replaces the pad-row memset for these columns).
__global__ __launch_bounds__(256)
void build_final_atom(const float* __restrict__ atom, unsigned short* __restrict__ out)
{
    const int idx = blockIdx.x * 256 + threadIdx.x;
    const int n = idx / 24, j = idx - n * 24;
    if (n >= NNP) return;
    const int c0 = j * 8;
    bf16x8 o;
#pragma unroll
    for (int i = 0; i < 8; ++i) {
        const int c = c0 + i;
        float v = (n < NN && c < 133) ? atom[(size_t)n * 133 + c] : 0.f;
        o[i] = (short)f2bf(v);
    }
    *(bf16x8*)(out + (size_t)n * 448 + 256 + c0) = o;
}

// ---------------------------------------------------------------------------
// Combined CSR build: counts/offsets over triplet keys [0,NE) + node keys
// [NE, NE+NN); one scan chain. plist: [0,NT) kj per triplet slot;
// [NT,NT+NE) edge id per node slot. count/fill each span NT+NE threads.
// ---------------------------------------------------------------------------
__global__ __launch_bounds__(256)
void count_both(const int* __restrict__ idx_ji, const int* __restrict__ dst,
                int* __restrict__ cnt)
{
    const int i = blockIdx.x * 256 + threadIdx.x;
    if (i < NT) {
        const int kk = idx_ji[i];
        if ((unsigned)kk < (unsigned)NE) atomicAdd(&cnt[kk], 1);
    } else {
        const int e = i - NT;
        if (e < NE) {
            const int kk = dst[e];
            if ((unsigned)kk < (unsigned)NN) atomicAdd(&cnt[NE + kk], 1);
        }
    }
}

__global__ __launch_bounds__(256)
void fill_both(const int* __restrict__ idx_ji, const int* __restrict__ idx_kj,
               const int* __restrict__ dst,
               int* __restrict__ cur, int* __restrict__ plist)
{
    const int i = blockIdx.x * 256 + threadIdx.x;
    if (i < NT) {
        const int kk = idx_ji[i];
        if ((unsigned)kk >= (unsigned)NE) return;
        const int pos = atomicAdd(&cur[kk], 1);
        if ((unsigned)pos < (unsigned)NT) plist[pos] = idx_kj[i];
    } else {
        const int e = i - NT;
        if (e >= NE) return;
        const int kk = dst[e];
        if ((unsigned)kk >= (unsigned)NN) return;
        const int pos = atomicAdd(&cur[NE + kk], 1);
        if ((unsigned)pos < (unsigned)(NT + NE)) plist[pos] = e;
    }
}

// per-block (2048 elems, 8/thread) exclusive scan; partials out (<=256 blocks)
__global__ __launch_bounds__(256)
void scan1(const int* __restrict__ in, int n, int* __restrict__ excl,
           int* __restrict__ part)
{
    __shared__ int sh[256];
    const int t = threadIdx.x;
    const int base = blockIdx.x * 2048 + t * 8;
    int v[8]; int s = 0;
#pragma unroll
    for (int j = 0; j < 8; ++j) { v[j] = (base + j < n) ? in[base + j] : 0; s += v[j]; }
    sh[t] = s; __syncthreads();
    for (int off = 1; off < 256; off <<= 1) {
        int x = (t >= off) ? sh[t - off] : 0;
        __syncthreads();
        sh[t] += x;
        __syncthreads();
    }
    int ex = sh[t] - s;
#pragma unroll
    for (int j = 0; j < 8; ++j) { if (base + j < n) excl[base + j] = ex; ex += v[j]; }
    if (t == 255) part[blockIdx.x] = sh[255];
}

__global__ __launch_bounds__(256)
void scan2(int* __restrict__ part, int nparts)
{
    __shared__ int sh[256];
    const int t = threadIdx.x;
    const int v = (t < nparts) ? part[t] : 0;
    sh[t] = v; __syncthreads();
    for (int off = 1; off < 256; off <<= 1) {
        int x = (t >= off) ? sh[t - off] : 0;
        __syncthreads();
        sh[t] += x;
        __syncthreads();
    }
    if (t < nparts) part[t] = sh[t] - v;
}

__global__ __launch_bounds__(256)
void scan3(const int* __restrict__ excl, const int* __restrict__ part,
           const int* counts, int n, int* __restrict__ offs, int* cur)
{
    const int i = blockIdx.x * 256 + threadIdx.x;
    if (i >= n) return;
    const int v = excl[i] + part[i >> 11];
    const int c = counts[i];
    offs[i] = v;
    cur[i] = v;
    if (i == n - 1) offs[n] = v + c;
}

// ---------------------------------------------------------------------------
// Fused attention gather: 16 lanes per edge (4 edges/wave) + 1-deep q/v
// value prefetch. Lane covers 16 dims (32 B); head reduce = 1 shfl_xor.
// ---------------------------------------------------------------------------
__global__ __launch_bounds__(256)
void gather_v(const unsigned short* __restrict__ q, const unsigned short* __restrict__ k,
              const unsigned short* __restrict__ v,
              const int* __restrict__ toff, const int* __restrict__ tkj,
              unsigned short* __restrict__ vc)
{
    const long gtid = (long)blockIdx.x * blockDim.x + threadIdx.x;
    const int w    = (int)(gtid >> 4);          // edge id
    const int lane = threadIdx.x & 15;          // 16 dims per lane
    if (w >= NE) return;
    int beg = toff[w], end = toff[w + 1];
    if (beg < 0) beg = 0;
    if (end > NT) end = NT;

    const size_t lo = (size_t)w * HID + lane * 16;
    const bf16x8 k0 = *(const bf16x8*)(k + lo);
    const bf16x8 k1 = *(const bf16x8*)(k + lo + 8);
    float kf[16];
#pragma unroll
    for (int j = 0; j < 8; ++j) { kf[j] = bf2f((unsigned short)k0[j]);
                                  kf[j + 8] = bf2f((unsigned short)k1[j]); }
    float av[16];
#pragma unroll
    for (int j = 0; j < 16; ++j) av[j] = 0.f;
    float den = 0.f;

    // prefetch slot
    bool okn = false; int an = 0;
    if (beg < end) {
        const int t0 = tkj[beg];
        okn = (unsigned)t0 < (unsigned)NE;
        an = okn ? t0 : 0;
    }
    bf16x8 qn0 = *(const bf16x8*)(q + (size_t)an * HID + lane * 16);
    bf16x8 qn1 = *(const bf16x8*)(q + (size_t)an * HID + lane * 16 + 8);
    bf16x8 vn0 = *(const bf16x8*)(v + (size_t)an * HID + lane * 16);
    bf16x8 vn1 = *(const bf16x8*)(v + (size_t)an * HID + lane * 16 + 8);

    for (int p = beg; p < end; ++p) {
        const bf16x8 q0 = qn0, q1 = qn1, v0 = vn0, v1 = vn1;
        const bool ok = okn;
        if (p + 1 < end) {
            const int tn = tkj[p + 1];
            okn = (unsigned)tn < (unsigned)NE;
            const int a2 = okn ? tn : 0;
            qn0 = *(const bf16x8*)(q + (size_t)a2 * HID + lane * 16);
            qn1 = *(const bf16x8*)(q + (size_t)a2 * HID + lane * 16 + 8);
            vn0 = *(const bf16x8*)(v + (size_t)a2 * HID + lane * 16);
            vn1 = *(const bf16x8*)(v + (size_t)a2 * HID + lane * 16 + 8);
        }
        if (!ok) continue;
        float s = 0.f;
#pragma unroll
        for (int j = 0; j < 8; ++j) {
            s += bf2f((unsigned short)q0[j]) * kf[j];
            s += bf2f((unsigned short)q1[j]) * kf[j + 8];
        }
        s += __shfl_xor(s, 1);                  // head = 2 lanes (d=32)
        const float lr = (s > 0.f) ? s : 0.2f * s;
        const float a  = __expf(lr);
        den += a;
#pragma unroll
        for (int j = 0; j < 8; ++j) {
            av[j]     += a * bf2f((unsigned short)v0[j]);
            av[j + 8] += a * bf2f((unsigned short)v1[j]);
        }
    }
    const float inv = (den != 0.f) ? 1.f / den : 0.f;
    bf16x8 o0, o1;
#pragma unroll
    for (int j = 0; j < 8; ++j) {
        o0[j] = (short)f2bf(av[j] * inv);
        o1[j] = (short)f2bf(av[j + 8] * inv);
    }
    *(bf16x8*)(vc + lo)     = o0;
    *(bf16x8*)(vc + lo + 8) = o1;
}

// ---------------------------------------------------------------------------
// edge->node gather: 16 lanes per node + value prefetch; writes bf16 directly
// into finalA cols [0,256) (row stride 448). Covers NNP rows — pad rows get
// zeros (replaces the memset for these columns).
// ---------------------------------------------------------------------------
__global__ __launch_bounds__(256)
void gather_node(const unsigned short* __restrict__ feats,
                 const int* __restrict__ noff, const int* __restrict__ nlist,
                 unsigned short* __restrict__ outA)
{
    const long gtid = (long)blockIdx.x * blockDim.x + threadIdx.x;
    const int w    = (int)(gtid >> 4);
    const int lane = threadIdx.x & 15;
    if (w >= NNP) return;
    unsigned short* out = outA + (size_t)w * 448 + lane * 16;
    if (w >= NN) {
        bf16x8 z = (bf16x8){0,0,0,0,0,0,0,0};
        *(bf16x8*)(out)     = z;
        *(bf16x8*)(out + 8) = z;
        return;
    }
    int beg = noff[w], end = noff[w + 1];
    if (beg < 0) beg = 0;
    if (end > NT + NE) end = NT + NE;

    float av[16];
#pragma unroll
    for (int j = 0; j < 16; ++j) av[j] = 0.f;

    bool okn = false; int an = 0;
    if (beg < end) {
        const int e0 = nlist[beg];
        okn = (unsigned)e0 < (unsigned)NE;
        an = okn ? e0 : 0;
    }
    bf16x8 fn0 = *(const bf16x8*)(feats + (size_t)an * HID + lane * 16);
    bf16x8 fn1 = *(const bf16x8*)(feats + (size_t)an * HID + lane * 16 + 8);

    for (int p = beg; p < end; ++p) {
        const bf16x8 f0 = fn0, f1 = fn1;
        const bool ok = okn;
        if (p + 1 < end) {
            const int en = nlist[p + 1];
            okn = (unsigned)en < (unsigned)NE;
            const int a2 = okn ? en : 0;
            fn0 = *(const bf16x8*)(feats + (size_t)a2 * HID + lane * 16);
            fn1 = *(const bf16x8*)(feats + (size_t)a2 * HID + lane * 16 + 8);
        }
        if (!ok) continue;
#pragma unroll
        for (int j = 0; j < 8; ++j) {
            av[j]     += bf2f((unsigned short)f0[j]);
            av[j + 8] += bf2f((unsigned short)f1[j]);
        }
    }
    bf16x8 o0, o1;
#pragma unroll
    for (int j = 0; j < 8; ++j) {
        o0[j] = (short)f2bf(av[j]);
        o1[j] = (short)f2bf(av[j + 8]);
    }
    *(bf16x8*)(out)     = o0;
    *(bf16x8*)(out + 8) = o1;
}

// ---------------------------------------------------------------------------
extern "C" void kernel_launch(void* const* d_in, const int* in_sizes, int n_in,
                              void* d_out, int out_size, void* d_ws, size_t ws_size,
                              hipStream_t stream)
{
    const float* atom = (const float*)d_in[0];
    const float* edge = (const float*)d_in[1];
    const float* W_i  = (const float*)d_in[2];
    const float* Wq   = (const float*)d_in[3];
    const float* Wk   = (const float*)d_in[4];
    const float* Wv   = (const float*)d_in[5];
    const float* L1w  = (const float*)d_in[6];
    const float* L1b  = (const float*)d_in[7];
    const float* L2w  = (const float*)d_in[8];
    const float* L2b  = (const float*)d_in[9];
    const float* Wo   = (const float*)d_in[10];
    const float* bo   = (const float*)d_in[11];
    const int* src    = (const int*)d_in[12];
    const int* dst    = (const int*)d_in[13];
    const int* idx_kj = (const int*)d_in[14];
    const int* idx_ji = (const int*)d_in[15];

    const size_t RB = (size_t)NE * HID * 2;   // 102,400,000 B
    char* ws = (char*)d_ws;
    unsigned short* feats = (unsigned short*)(ws);
    unsigned short* qb    = (unsigned short*)(ws + RB);
    unsigned short* kb    = (unsigned short*)(ws + 2 * RB);
    unsigned short* vb    = (unsigned short*)d_out;     // NE*256 bf16 == d_out bytes
    unsigned short* vc    = feats;                      // v_clone overlays feats
    unsigned short* initA = qb;                         // NEP*192 bf16 = 76.8MB < RB
    unsigned short* h1    = kb;
    unsigned short* finalA = kb;                        // NNP*448 bf16 = 89.7MB < RB

    const int NK = NE + NN;                 // combined key count
    char* p = ws + 3 * RB;
    int* offs     = (int*)p; p += ((size_t)NK + 16) * 4;
    int* cur      = (int*)p; p += ((size_t)NK + 16) * 4;
    int* plist    = (int*)p; p += (size_t)(NT + NE) * 4;
    int* tmp_excl = (int*)p; p += ((size_t)NK + 16) * 4;
    int* partials = (int*)p; p += 1024;
    unsigned short* wiT = (unsigned short*)p; p += (size_t)256 * 192 * 2;
    unsigned short* wT0 = (unsigned short*)p; p += (size_t)10 * 65536 * 2;
    unsigned short* woT = (unsigned short*)p; p += (size_t)256 * 448 * 2;
    const size_t NEEDED = (size_t)(p - ws);
    if (ws_size < NEEDED) return;
    auto wT = [&](int i) { return wT0 + (size_t)i * 65536; };

    const int MT_E  = NEP / 128;                 // 1563 M-tiles (edge GEMMs)
    const int MT_E8 = ((MT_E + 7) / 8) * 8;      // 1568
    const int MT_N  = NNP / 128;                 // 782 (final GEMM)
    const int MT_N8 = ((MT_N + 7) / 8) * 8;      // 784
    const int NPARTS = (NK + 2047) / 2048;       // 147 <= 256

    // ---- all weight conversions (one launch) ----
    wconv_all<<<dim3(448, 12), 256, 0, stream>>>(Wq, Wk, Wv, L1w, L2w, W_i, Wo,
                                                 wT0, wiT, woT);

    // ---- combined CSR build ----
    hipMemsetAsync(cur, 0, (size_t)NK * 4, stream);
    count_both<<<(NT + NE + 255) / 256, 256, 0, stream>>>(idx_ji, dst, cur);
    scan1<<<NPARTS, 256, 0, stream>>>(cur, NK, tmp_excl, partials);
    scan2<<<1, 256, 0, stream>>>(partials, NPARTS);
    scan3<<<(NK + 255) / 256, 256, 0, stream>>>(tmp_excl, partials, cur, NK, offs, cur);
    fill_both<<<(NT + NE + 255) / 256, 256, 0, stream>>>(idx_ji, idx_kj, dst, cur, plist);

    // ---- init: feats = relu(concat(atom[src], edge) @ W_i) ----
    build_initA<<<(NE * 24 + 255) / 256, 256, 0, stream>>>(atom, edge, src, initA);
    gemm128<1, true><<<MT_E8 * 2, 256, 0, stream>>>(initA, wiT, nullptr, nullptr,
                                                    feats, MT_E, NE, 192);

    // ---- 2 attention layers ----
    for (int l = 0; l < 2; ++l) {
        const float* l1b = L1b + (size_t)l * 256;
        const float* l2b = L2b + (size_t)l * 256;

        gemm128_qkv<<<MT_E8 * 6, 256, 0, stream>>>(
            feats, wT(l * 5 + 0), wT(l * 5 + 1), wT(l * 5 + 2), qb, kb, vb, MT_E);

        gather_v<<<(NE * 16) / 256, 256, 0, stream>>>(qb, kb, vb, offs, plist, vc);

        // h1 = relu(vc @ L1 + b1); feats = v + relu(h1 @ L2 + b2)
        gemm128<3, true><<<MT_E8 * 2, 256, 0, stream>>>(vc, wT(l * 5 + 3), l1b,
                                                        nullptr, h1, MT_E, NE, 256);
        gemm128<7, true><<<MT_E8 * 2, 256, 0, stream>>>(h1, wT(l * 5 + 4), l2b,
                                                        vb, feats, MT_E, NE, 256);
    }

    // ---- final projection: finalA = [fsum | atom | 0] (permuted K) ----
    gather_node<<<(NNP * 16 + 255) / 256, 256, 0, stream>>>(feats, offs + NE, plist, finalA);
    build_final_atom<<<(NNP * 24 + 255) / 256, 256, 0, stream>>>(atom, finalA);
    gemm128<3, false><<<MT_N8 * 2, 256, 0, stream>>>(finalA, woT, bo, nullptr,
                                                     d_out, MT_N, NN, 448);
}